// Round 5
// baseline (1353.165 us; speedup 1.0000x reference)
//
#include <hip/hip_runtime.h>

typedef unsigned int u32;
typedef unsigned short u16;
typedef _Float16 f16x2 __attribute__((ext_vector_type(2)));

// ---------------- problem constants ----------------
// B=32, T=32, F=64, H=256, N=1024, A=64, C=192, M=256
// out: hs [32,256,32] (262144 f32) then outs [32,10,32] (10240 f32)

// ---------------- workspace (u32 offsets), all k4-packed uint4 [panel][k4][64] ----------------
#define WP_A0    0        // [Wh0;Wi0] 4 panels x 40 k4   (pairs: h 0..127, x 128..159)
#define WP_A1    40960
#define WP_A2H   81920    // Wh2 4 x 32
#define WP_A2I   114688   // Wi2 4 x 8
#define WP_AQ    122880   // Wq  4 x 32
#define WP_AC    155648   // [Wch;Wci] 3 x 40
#define WP_AM    186368   // Wm  12 x 32 (gate-major)
#define WP_AT2   284672   // maddr row-pairs: 16 panels x 8 k4 (outs n, k a)
#define WP_M4    317440   // maddr col view: [128 k4][64 a]  (outs a, k n-pairs)
#define WP_WO4   350208   // W_output: [10][32] uint4

// ---------------- LDS layout (f32 offsets) ----------------
#define SH_HX    0      // f32 h[256]
#define SH_H2    256    // u32[160] (h,x) f16 pairs
#define SH_Q     416    // f32 q[256] (incl bq)
#define SH_Q2    672    // u32[32]  q[0..63] f16 pairs
#define SH_GA0   704    // f32 [256]
#define SH_GA1   960    // f32 [256]
#define SH_GH2A  1216   // f32 [256]  Wh2 k-half 0
#define SH_GH2B  1472   // f32 [256]  Wh2 k-half 1
#define SH_GI2   1728   // f32 [256]
#define SH_GM    1984   // f32 [3][256]
#define SH_SIMA  2752   // f32 [1024]
#define SH_R2    3776   // u32 [128] reading f16 pairs
#define SH_D     3904   // f32 [32]
#define SH_G     3936   // f32 [32]
#define SH_RED   3968   // f32 [16]
#define SH_RED2  3984   // f32 [16]
#define SH_MISC  4000   // f32 [8]  [0]=beta
#define SH_B10   4008   // f32 [16]
#define SH_RA    4024   // f32 [8][64] reading_a partials
#define SH_CAND  4536   // u16[32*192] = 3072 f32 slots
#define SH_W     7608   // u16[32][1024] = 16384 f32 slots
#define SMEM_FLOATS 23992
#define SMEM_BYTES (SMEM_FLOATS*4)

#define WRED(v) { v += __shfl_xor(v,32); v += __shfl_xor(v,16); v += __shfl_xor(v,8); \
                  v += __shfl_xor(v,4);  v += __shfl_xor(v,2);  v += __shfl_xor(v,1); }

__device__ __forceinline__ f16x2 bch2(u32 u) { return __builtin_bit_cast(f16x2, u); }

#if __has_builtin(__builtin_amdgcn_fdot2)
__device__ __forceinline__ float FDOT2(u32 a, u32 b, float c) {
  return __builtin_amdgcn_fdot2(bch2(a), bch2(b), c, false);
}
#else
__device__ __forceinline__ float FDOT2(u32 a, u32 b, float c) {
  f16x2 x = bch2(a), y = bch2(b);
  return c + (float)x[0]*(float)y[0] + (float)x[1]*(float)y[1];
}
#endif

__device__ __forceinline__ u16 f2h(float x) {
  _Float16 h = (_Float16)x; return __builtin_bit_cast(u16, h);
}
__device__ __forceinline__ float h2f(u16 u) {
  return (float)__builtin_bit_cast(_Float16, u);
}
__device__ __forceinline__ u32 packh2(float lo, float hi) {
  return (u32)f2h(lo) | ((u32)f2h(hi) << 16);
}

// ---- k4-packed matvec: 1 out/lane, layout [k4][64] uint4.
// 4-k4 groups, 2-group lookahead software pipeline, all NAMED registers
// (bounded VGPR by construction, no arrays -> no scratch). NK4 % 4 == 0.
template<int NK4>
__device__ __forceinline__ float mv_os4(const u32* __restrict__ Wb,
                                        const u32* __restrict__ c2, const int ln)
{
  static_assert(NK4 % 4 == 0, "NK4 must be multiple of 4");
  constexpr int NG = NK4 / 4;
  const uint4* __restrict__ wp = (const uint4*)Wb + ln;
  const uint4* __restrict__ c4 = (const uint4*)c2;
  float a0 = 0.f, a1 = 0.f, a2 = 0.f, a3 = 0.f;
  uint4 wa0, wa1, wa2, wa3, ca0, ca1, ca2, ca3;
  uint4 wb0, wb1, wb2, wb3, cb0, cb1, cb2, cb3;
#define LWA_(g) { wa0 = wp[(g)*256]; wa1 = wp[(g)*256+64]; wa2 = wp[(g)*256+128]; wa3 = wp[(g)*256+192]; \
                  ca0 = c4[(g)*4];   ca1 = c4[(g)*4+1];    ca2 = c4[(g)*4+2];     ca3 = c4[(g)*4+3]; }
#define LWB_(g) { wb0 = wp[(g)*256]; wb1 = wp[(g)*256+64]; wb2 = wp[(g)*256+128]; wb3 = wp[(g)*256+192]; \
                  cb0 = c4[(g)*4];   cb1 = c4[(g)*4+1];    cb2 = c4[(g)*4+2];     cb3 = c4[(g)*4+3]; }
#define CMPA_ { a0=FDOT2(wa0.x,ca0.x,a0); a1=FDOT2(wa0.y,ca0.y,a1); a2=FDOT2(wa0.z,ca0.z,a2); a3=FDOT2(wa0.w,ca0.w,a3); \
                a0=FDOT2(wa1.x,ca1.x,a0); a1=FDOT2(wa1.y,ca1.y,a1); a2=FDOT2(wa1.z,ca1.z,a2); a3=FDOT2(wa1.w,ca1.w,a3); \
                a0=FDOT2(wa2.x,ca2.x,a0); a1=FDOT2(wa2.y,ca2.y,a1); a2=FDOT2(wa2.z,ca2.z,a2); a3=FDOT2(wa2.w,ca2.w,a3); \
                a0=FDOT2(wa3.x,ca3.x,a0); a1=FDOT2(wa3.y,ca3.y,a1); a2=FDOT2(wa3.z,ca3.z,a2); a3=FDOT2(wa3.w,ca3.w,a3); }
#define CMPB_ { a0=FDOT2(wb0.x,cb0.x,a0); a1=FDOT2(wb0.y,cb0.y,a1); a2=FDOT2(wb0.z,cb0.z,a2); a3=FDOT2(wb0.w,cb0.w,a3); \
                a0=FDOT2(wb1.x,cb1.x,a0); a1=FDOT2(wb1.y,cb1.y,a1); a2=FDOT2(wb1.z,cb1.z,a2); a3=FDOT2(wb1.w,cb1.w,a3); \
                a0=FDOT2(wb2.x,cb2.x,a0); a1=FDOT2(wb2.y,cb2.y,a1); a2=FDOT2(wb2.z,cb2.z,a2); a3=FDOT2(wb2.w,cb2.w,a3); \
                a0=FDOT2(wb3.x,cb3.x,a0); a1=FDOT2(wb3.y,cb3.y,a1); a2=FDOT2(wb3.z,cb3.z,a2); a3=FDOT2(wb3.w,cb3.w,a3); }
  LWA_(0);
  if constexpr (NG == 1) {
    CMPA_;
  } else {
    LWB_(1);
    #pragma unroll
    for (int g = 0; g + 2 < NG; ++g) {
      if ((g & 1) == 0) { CMPA_; LWA_(g + 2); }
      else              { CMPB_; LWB_(g + 2); }
    }
    if constexpr (((NG - 2) & 1) == 0) { CMPA_; CMPB_; }
    else                               { CMPB_; CMPA_; }
  }
#undef LWA_
#undef LWB_
#undef CMPA_
#undef CMPB_
  return (a0 + a1) + (a2 + a3);
}

// ---- dual-panel NK4=8 matvec: two 64-out panels over the SAME coef (shared c),
// one pipeline prologue, <=8 uint4 w-loads in flight. Returns (panel0, panel1).
__device__ __forceinline__ float2 mv2_os4_8(const u32* __restrict__ W0,
    const u32* __restrict__ W1, const u32* __restrict__ c2, const int ln)
{
  const uint4* __restrict__ w0p = (const uint4*)W0 + ln;
  const uint4* __restrict__ w1p = (const uint4*)W1 + ln;
  const uint4* __restrict__ c4 = (const uint4*)c2;
  float a0=0.f,a1=0.f,a2=0.f,a3=0.f, b0=0.f,b1=0.f,b2=0.f,b3=0.f;
  uint4 wa0=w0p[0],   wa1=w0p[64],  wa2=w0p[128], wa3=w0p[192];
  uint4 ca0=c4[0],    ca1=c4[1],    ca2=c4[2],    ca3=c4[3];
  uint4 wb0=w0p[256], wb1=w0p[320], wb2=w0p[384], wb3=w0p[448];
  uint4 cb0=c4[4],    cb1=c4[5],    cb2=c4[6],    cb3=c4[7];
  // P0 g0
  a0=FDOT2(wa0.x,ca0.x,a0); a1=FDOT2(wa0.y,ca0.y,a1); a2=FDOT2(wa0.z,ca0.z,a2); a3=FDOT2(wa0.w,ca0.w,a3);
  a0=FDOT2(wa1.x,ca1.x,a0); a1=FDOT2(wa1.y,ca1.y,a1); a2=FDOT2(wa1.z,ca1.z,a2); a3=FDOT2(wa1.w,ca1.w,a3);
  a0=FDOT2(wa2.x,ca2.x,a0); a1=FDOT2(wa2.y,ca2.y,a1); a2=FDOT2(wa2.z,ca2.z,a2); a3=FDOT2(wa2.w,ca2.w,a3);
  a0=FDOT2(wa3.x,ca3.x,a0); a1=FDOT2(wa3.y,ca3.y,a1); a2=FDOT2(wa3.z,ca3.z,a2); a3=FDOT2(wa3.w,ca3.w,a3);
  wa0=w1p[0]; wa1=w1p[64]; wa2=w1p[128]; wa3=w1p[192];     // P1 g0
  // P0 g1
  a0=FDOT2(wb0.x,cb0.x,a0); a1=FDOT2(wb0.y,cb0.y,a1); a2=FDOT2(wb0.z,cb0.z,a2); a3=FDOT2(wb0.w,cb0.w,a3);
  a0=FDOT2(wb1.x,cb1.x,a0); a1=FDOT2(wb1.y,cb1.y,a1); a2=FDOT2(wb1.z,cb1.z,a2); a3=FDOT2(wb1.w,cb1.w,a3);
  a0=FDOT2(wb2.x,cb2.x,a0); a1=FDOT2(wb2.y,cb2.y,a1); a2=FDOT2(wb2.z,cb2.z,a2); a3=FDOT2(wb2.w,cb2.w,a3);
  a0=FDOT2(wb3.x,cb3.x,a0); a1=FDOT2(wb3.y,cb3.y,a1); a2=FDOT2(wb3.z,cb3.z,a2); a3=FDOT2(wb3.w,cb3.w,a3);
  wb0=w1p[256]; wb1=w1p[320]; wb2=w1p[384]; wb3=w1p[448];  // P1 g1
  // P1 g0
  b0=FDOT2(wa0.x,ca0.x,b0); b1=FDOT2(wa0.y,ca0.y,b1); b2=FDOT2(wa0.z,ca0.z,b2); b3=FDOT2(wa0.w,ca0.w,b3);
  b0=FDOT2(wa1.x,ca1.x,b0); b1=FDOT2(wa1.y,ca1.y,b1); b2=FDOT2(wa1.z,ca1.z,b2); b3=FDOT2(wa1.w,ca1.w,b3);
  b0=FDOT2(wa2.x,ca2.x,b0); b1=FDOT2(wa2.y,ca2.y,b1); b2=FDOT2(wa2.z,ca2.z,b2); b3=FDOT2(wa2.w,ca2.w,b3);
  b0=FDOT2(wa3.x,ca3.x,b0); b1=FDOT2(wa3.y,ca3.y,b1); b2=FDOT2(wa3.z,ca3.z,b2); b3=FDOT2(wa3.w,ca3.w,b3);
  // P1 g1
  b0=FDOT2(wb0.x,cb0.x,b0); b1=FDOT2(wb0.y,cb0.y,b1); b2=FDOT2(wb0.z,cb0.z,b2); b3=FDOT2(wb0.w,cb0.w,b3);
  b0=FDOT2(wb1.x,cb1.x,b0); b1=FDOT2(wb1.y,cb1.y,b1); b2=FDOT2(wb1.z,cb1.z,b2); b3=FDOT2(wb1.w,cb1.w,b3);
  b0=FDOT2(wb2.x,cb2.x,b0); b1=FDOT2(wb2.y,cb2.y,b1); b2=FDOT2(wb2.z,cb2.z,b2); b3=FDOT2(wb2.w,cb2.w,b3);
  b0=FDOT2(wb3.x,cb3.x,b0); b1=FDOT2(wb3.y,cb3.y,b1); b2=FDOT2(wb3.z,cb3.z,b2); b3=FDOT2(wb3.w,cb3.w,b3);
  return make_float2((a0+a1)+(a2+a3), (b0+b1)+(b2+b3));
}

__device__ __forceinline__ void out_lse(const float* __restrict__ b10,
    float* __restrict__ out, const int t_out, const int bb, const int ln)
{
  float v = (ln < 10) ? b10[ln] : -1e30f;
  float m = v;
  m = fmaxf(m, __shfl_xor(m, 8, 16));
  m = fmaxf(m, __shfl_xor(m, 4, 16));
  m = fmaxf(m, __shfl_xor(m, 2, 16));
  m = fmaxf(m, __shfl_xor(m, 1, 16));
  float e = (ln < 10) ? __expf(v - m) : 0.f;
  float s = e;
  s += __shfl_xor(s, 8, 16);
  s += __shfl_xor(s, 4, 16);
  s += __shfl_xor(s, 2, 16);
  s += __shfl_xor(s, 1, 16);
  if (ln < 10) out[262144 + t_out * 320 + ln * 32 + bb] = v - m - logf(s);
}

// ---------------- pack kernel ----------------
__device__ __forceinline__ void pack_panel(const float* __restrict__ srcA, int KA, int np4A,
                                           const float* __restrict__ srcB, int KB,
                                           int np4tot, int o0, u32* __restrict__ dstu, int tid)
{
  uint4* d4 = (uint4*)dstu;
  for (int idx = tid; idx < np4tot * 64; idx += 256) {
    const int k4 = idx >> 6, o = idx & 63;
    const float* s = (k4 < np4A) ? (srcA + (size_t)(o0 + o) * KA + k4 * 8)
                                 : (srcB + (size_t)(o0 + o) * KB + (k4 - np4A) * 8);
    uint4 v;
    v.x = packh2(s[0], s[1]); v.y = packh2(s[2], s[3]);
    v.z = packh2(s[4], s[5]); v.w = packh2(s[6], s[7]);
    d4[idx] = v;
  }
}

__global__ void pack_weights(const float* __restrict__ Wi, const float* __restrict__ Wh,
                             const float* __restrict__ Wm, const float* __restrict__ Wq,
                             const float* __restrict__ Wch, const float* __restrict__ Wci,
                             const float* __restrict__ maddr, const float* __restrict__ Wo,
                             u32* __restrict__ wsu)
{
  const int b = blockIdx.x, tid = threadIdx.x;
  if (b < 4)        pack_panel(Wh,          256, 32, Wi,        64, 40, b*64,      wsu + WP_A0  + b*10240, tid);
  else if (b < 8)   pack_panel(Wh + 65536,  256, 32, Wi + 16384,64, 40, (b-4)*64,  wsu + WP_A1  + (b-4)*10240, tid);
  else if (b < 12)  pack_panel(Wh + 131072, 256, 32, Wh,       256, 32, (b-8)*64,  wsu + WP_A2H + (b-8)*8192, tid);
  else if (b < 16)  pack_panel(Wi + 32768,   64,  8, Wi,        64,  8, (b-12)*64, wsu + WP_A2I + (b-12)*2048, tid);
  else if (b < 20)  pack_panel(Wq,          256, 32, Wq,       256, 32, (b-16)*64, wsu + WP_AQ  + (b-16)*8192, tid);
  else if (b < 23)  pack_panel(Wch,         256, 32, Wci,       64, 40, (b-20)*64, wsu + WP_AC  + (b-20)*10240, tid);
  else if (b < 35) { int x = b-23; int g = x>>2;
                    pack_panel(Wm + g*65536, 256, 32, Wm,      256, 32, (x&3)*64,  wsu + WP_AM  + x*8192, tid); }
  else if (b < 51)  pack_panel(maddr,        64,  8, maddr,     64,  8, (b-35)*64, wsu + WP_AT2 + (b-35)*2048, tid);
  else if (b < 55) { // M4: uint4(k4, a) = n-pairs 4k4..4k4+3 of maddr column a
    const int kb = b - 51;
    uint4* d4 = (uint4*)(wsu + WP_M4);
    for (int idx = tid; idx < 2048; idx += 256) {
      const int k4 = kb*32 + (idx >> 6), a = idx & 63;
      const float* s = maddr + (size_t)(8*k4)*64 + a;
      uint4 v;
      v.x = packh2(s[0],   s[64]);  v.y = packh2(s[128], s[192]);
      v.z = packh2(s[256], s[320]); v.w = packh2(s[384], s[448]);
      d4[k4*64 + a] = v;
    }
  } else {          // WO4: [10][32] uint4 = pack8(Wo[j][8l..8l+8])
    uint4* d4 = (uint4*)(wsu + WP_WO4);
    for (int idx = tid; idx < 320; idx += 256) {
      const int j = idx >> 5, l = idx & 31;
      const float* s = Wo + j*256 + l*8;
      uint4 v;
      v.x = packh2(s[0], s[1]); v.y = packh2(s[2], s[3]);
      v.z = packh2(s[4], s[5]); v.w = packh2(s[6], s[7]);
      d4[idx] = v;
    }
  }
}

// ---------------- main persistent per-batch kernel ----------------
__global__ __launch_bounds__(1024, 4) void dntm_step(
    const float* __restrict__ batch, const float* __restrict__ bi,
    const float* __restrict__ bh, const float* __restrict__ bm,
    const float* __restrict__ bo, const float* __restrict__ bq,
    const float* __restrict__ usharp, const u32* __restrict__ wsu,
    float* __restrict__ out)
{
  extern __shared__ float sm[];
  u32* h2u   = (u32*)(sm + SH_H2);
  u32* Q2u   = (u32*)(sm + SH_Q2);
  u32* R2u   = (u32*)(sm + SH_R2);
  u16* candh = (u16*)(sm + SH_CAND);
  u16* SW16  = (u16*)(sm + SH_W);
  u32* SW32  = (u32*)(sm + SH_W);
  const int tid = threadIdx.x, ln = tid & 63, wv = tid >> 6;
  const int bb = blockIdx.x;

  if (tid < 256) sm[SH_HX + tid] = 0.f;
  if (tid < 128) h2u[tid] = 0u;
  if (tid >= 128 && tid < 160) {
    const int j = tid - 128;
    const int i0 = (2*j)*32 + bb, i1 = i0 + 32;
    const float x0 = batch[(i0 >> 6)*2048 + (i0 & 63)];
    const float x1 = batch[(i1 >> 6)*2048 + (i1 & 63)];
    h2u[128 + j] = packh2(x0, x1);
  }
  __syncthreads();

  for (int t = 0; t < 32; ++t) {
    // ===== P1: all h/x matvecs (f16 dot2), balanced ~40-56 k4 per wave =====
    if (wv < 8) {
      if (wv < 4) {
        sm[SH_GA0 + wv*64 + ln] = mv_os4<40>(wsu + WP_A0 + wv*10240, h2u, ln);
      } else {
        sm[SH_GA1 + (wv-4)*64 + ln] = mv_os4<40>(wsu + WP_A1 + (wv-4)*10240, h2u, ln);
      }
      // Wh2 half-panel: half index = wv (panel wv>>1, k-part wv&1)
      const int p = wv >> 1, pt = wv & 1;
      const float hv = mv_os4<16>(wsu + WP_A2H + p*8192 + pt*4096, h2u + pt*64, ln);
      sm[(pt ? SH_GH2B : SH_GH2A) + p*64 + ln] = hv;
    } else if (wv < 11) {
      const int p = wv - 8;
      const float cv = mv_os4<40>(wsu + WP_AC + p*10240, h2u, ln);
      candh[t*192 + p*64 + ln] = f2h(fmaxf(cv, 0.f));
    } else if (wv == 11) {
      const float2 r01 = mv2_os4_8(wsu+WP_A2I,        wsu+WP_A2I+2048, h2u+128, ln);
      const float2 r23 = mv2_os4_8(wsu+WP_A2I+4096,   wsu+WP_A2I+6144, h2u+128, ln);
      sm[SH_GI2 +       ln] = r01.x; sm[SH_GI2 +  64 + ln] = r01.y;
      sm[SH_GI2 + 128 + ln] = r23.x; sm[SH_GI2 + 192 + ln] = r23.y;
      { // beta = softplus(u.h) + 1  (f32)
        const float4 h4 = *(const float4*)(sm + SH_HX + ln*4);
        const float4 u4 = *(const float4*)(usharp + ln*4);
        float v = h4.x*u4.x + h4.y*u4.y + h4.z*u4.z + h4.w*u4.w;
        WRED(v);
        if (!ln) sm[SH_MISC] = fmaxf(v, 0.f) + log1pf(expf(-fabsf(v))) + 1.f;
      }
    } else {
      const int p = wv - 12;
      const float qv = mv_os4<32>(wsu + WP_AQ + p*8192, h2u, ln) + bq[p*64 + ln];
      sm[SH_Q + p*64 + ln] = qv;
      if (wv == 12) {
        const float qh = __shfl_down(qv, 1);
        if (!(ln & 1)) Q2u[ln >> 1] = packh2(qv, qh);
      }
      if (wv == 13 && t > 0) { // logits of h_t == h_new(t-1), f16 Wo x f16 h pairs
        const uint4 ch = ((const uint4*)h2u)[ln & 31];
        const uint4* wo4 = (const uint4*)(wsu + WP_WO4);
        for (int j = 0; j < 10; ++j) {
          float lv = 0.f;
          if (ln < 32) {
            const uint4 w4 = wo4[j*32 + ln];
            lv = FDOT2(w4.x, ch.x, lv); lv = FDOT2(w4.y, ch.y, lv);
            lv = FDOT2(w4.z, ch.z, lv); lv = FDOT2(w4.w, ch.w, lv);
          }
          WRED(lv);
          if (!ln) sm[SH_B10 + j] = lv + bo[j];
        }
      }
    }
    __syncthreads();

    // ===== P2: sim addr-part (dual-panel f16 dot2); d[s] = cand_s . q_c; out_lse(t-1) =====
    if (wv < 8) {
      const float2 r = mv2_os4_8(wsu + WP_AT2 + (2*wv)*2048,
                                 wsu + WP_AT2 + (2*wv+1)*2048, Q2u, ln);
      sm[SH_SIMA + wv*128 + ln]      = r.x;
      sm[SH_SIMA + wv*128 + 64 + ln] = r.y;
    } else if (wv < 15) {
      const float q0 = sm[SH_Q + 64 + ln], q1 = sm[SH_Q + 128 + ln], q2 = sm[SH_Q + 192 + ln];
      for (int s = wv - 8; s < t; s += 7) {
        float a2 = h2f(candh[s*192 + ln]) * q0
                 + h2f(candh[s*192 + 64 + ln]) * q1
                 + h2f(candh[s*192 + 128 + ln]) * q2;
        WRED(a2);
        if (!ln) sm[SH_D + s] = a2;
      }
    } else {
      if (t > 0) out_lse(sm + SH_B10, out, t - 1, bb, ln);
    }
    __syncthreads();

    // ===== P3: v = beta*(sim_a + sum_s d[s] w_s[n]); wave max =====
    const int n3 = wv * 64 + ln;
    float v = sm[SH_SIMA + n3];
    #pragma unroll 4
    for (int s = 0; s < t; ++s) v = fmaf(sm[SH_D + s], h2f(SW16[s*1024 + n3]), v);
    v *= sm[SH_MISC];
    {
      float mx = v;
      mx = fmaxf(mx, __shfl_xor(mx, 32)); mx = fmaxf(mx, __shfl_xor(mx, 16));
      mx = fmaxf(mx, __shfl_xor(mx, 8));  mx = fmaxf(mx, __shfl_xor(mx, 4));
      mx = fmaxf(mx, __shfl_xor(mx, 2));  mx = fmaxf(mx, __shfl_xor(mx, 1));
      if (!ln) sm[SH_RED + wv] = mx;
    }
    __syncthreads();

    // ===== P4: e = exp(v - gmax) -> f16 history row t (unnormalized); wave sums =====
    {
      float gmx = sm[SH_RED];
      #pragma unroll
      for (int i = 1; i < 16; ++i) gmx = fmaxf(gmx, sm[SH_RED + i]);
      const float e = __expf(v - gmx);
      SW16[t*1024 + n3] = f2h(e);
      float s2 = e; WRED(s2);
      if (!ln) sm[SH_RED2 + wv] = s2;
    }
    __syncthreads();

    // ===== P5: reading_a partials (M4 k4-packed); g[s] = w_s . w_t =====
    {
      float tot = 0.f;
      #pragma unroll
      for (int i = 0; i < 16; ++i) tot += sm[SH_RED2 + i];
      const float inv = 1.0f / tot;
      if (wv < 8) {
        const float acc = mv_os4<16>(wsu + WP_M4 + wv*16*256,
                                     SW32 + t*512 + wv*64, ln);
        sm[SH_RA + wv*64 + ln] = acc * inv;
      } else {
        const uint4 ea = ((const uint4*)(SW32 + t*512))[ln*2];
        const uint4 eb = ((const uint4*)(SW32 + t*512))[ln*2 + 1];
        for (int s = wv - 8; s < t; s += 8) {
          const uint4 wa = ((const uint4*)(SW32 + s*512))[ln*2];
          const uint4 wb = ((const uint4*)(SW32 + s*512))[ln*2 + 1];
          float a2 = 0.f;
          a2 = FDOT2(ea.x, wa.x, a2); a2 = FDOT2(ea.y, wa.y, a2);
          a2 = FDOT2(ea.z, wa.z, a2); a2 = FDOT2(ea.w, wa.w, a2);
          a2 = FDOT2(eb.x, wb.x, a2); a2 = FDOT2(eb.y, wb.y, a2);
          a2 = FDOT2(eb.z, wb.z, a2); a2 = FDOT2(eb.w, wb.w, a2);
          WRED(a2);
          if (!ln) sm[SH_G + s] = a2 * inv;
        }
      }
    }
    __syncthreads();

    // ===== P6: assemble reading -> f16 pairs R2 =====
    if (wv == 0) {
      float r = 0.f;
      #pragma unroll
      for (int j = 0; j < 8; ++j) r += sm[SH_RA + j*64 + ln];
      const float rh = __shfl_down(r, 1);
      if (!(ln & 1)) R2u[ln >> 1] = packh2(r, rh);
    } else if (wv < 4) {
      const int c = (wv - 1)*64 + ln;
      float r = 0.f;
      for (int s = 0; s < t; ++s) r = fmaf(h2f(candh[s*192 + c]), sm[SH_G + s], r);
      const float rh = __shfl_down(r, 1);
      if (!(ln & 1)) R2u[wv*32 + (ln >> 1)] = packh2(r, rh);
    }
    __syncthreads();

    // ===== P7: gm = Wm @ reading (12 waves, full K); normalize w row; prefetch x =====
    if (wv < 12) {
      const int g = wv >> 2, p = wv & 3;
      sm[SH_GM + g*256 + p*64 + ln] = mv_os4<32>(wsu + WP_AM + wv*8192, R2u, ln);
    } else if (wv < 14) {
      float tot = 0.f;
      #pragma unroll
      for (int i = 0; i < 16; ++i) tot += sm[SH_RED2 + i];
      const float inv = 1.0f / tot;
      u32* p = SW32 + t*512 + (wv - 12)*256 + ln*4;
      uint4 v4 = *(const uint4*)p;
      v4.x = packh2(h2f(v4.x & 0xffff)*inv, h2f(v4.x >> 16)*inv);
      v4.y = packh2(h2f(v4.y & 0xffff)*inv, h2f(v4.y >> 16)*inv);
      v4.z = packh2(h2f(v4.z & 0xffff)*inv, h2f(v4.z >> 16)*inv);
      v4.w = packh2(h2f(v4.w & 0xffff)*inv, h2f(v4.w >> 16)*inv);
      *(uint4*)p = v4;
    } else if (wv == 14) {
      if (t < 31 && ln < 32) {
        const int i0 = (2*ln)*32 + bb, i1 = i0 + 32;
        const float x0 = batch[(i0 >> 6)*2048 + (t+1)*64 + (i0 & 63)];
        const float x1 = batch[(i1 >> 6)*2048 + (t+1)*64 + (i1 & 63)];
        h2u[128 + ln] = packh2(x0, x1);
      }
    }
    __syncthreads();

    // ===== P8: gate combine, h update, hs output, pack h pairs =====
    if (tid < 256) {
      const int h = tid;
      const float g0  = sm[SH_GA0 + h] + bi[h]       + bh[h]       + sm[SH_GM + h]       + bm[h];
      const float g1  = sm[SH_GA1 + h] + bi[256 + h] + bh[256 + h] + sm[SH_GM + 256 + h] + bm[256 + h];
      const float gh2v = sm[SH_GH2A + h] + sm[SH_GH2B + h] + bh[512 + h];
      const float gi2v = sm[SH_GI2 + h] + bi[512 + h];
      const float gm2  = sm[SH_GM + 512 + h] + bm[512 + h];
      const float r = 1.f / (1.f + __expf(-g0));
      const float z = 1.f / (1.f + __expf(-g1));
      const float nn = tanhf(gi2v + gm2 + r * gh2v);
      const float hn = (1.f - z) * nn + z * sm[SH_HX + h];
      sm[SH_HX + h] = hn;
      out[t*8192 + h*32 + bb] = hn;
      const float hn1 = __shfl_down(hn, 1);
      if (!(tid & 1)) h2u[tid >> 1] = packh2(hn, hn1);
    }
    __syncthreads();
  }

  // ---- epilogue: out[31] ----
  if (wv == 0) {
    const uint4 ch = ((const uint4*)h2u)[ln & 31];
    const uint4* wo4 = (const uint4*)(wsu + WP_WO4);
    for (int j = 0; j < 10; ++j) {
      float lv = 0.f;
      if (ln < 32) {
        const uint4 w4 = wo4[j*32 + ln];
        lv = FDOT2(w4.x, ch.x, lv); lv = FDOT2(w4.y, ch.y, lv);
        lv = FDOT2(w4.z, ch.z, lv); lv = FDOT2(w4.w, ch.w, lv);
      }
      WRED(lv);
      if (!ln) sm[SH_B10 + j] = lv + bo[j];
    }
    out_lse(sm + SH_B10, out, 31, bb, ln);
  }
}

extern "C" void kernel_launch(void* const* d_in, const int* in_sizes, int n_in,
                              void* d_out, int out_size, void* d_ws, size_t ws_size,
                              hipStream_t stream) {
  (void)in_sizes; (void)n_in; (void)out_size; (void)ws_size;
  const float* batch = (const float*)d_in[0];
  const float* Wi    = (const float*)d_in[1];
  const float* bi    = (const float*)d_in[2];
  const float* Wh    = (const float*)d_in[3];
  const float* bh    = (const float*)d_in[4];
  const float* Wm    = (const float*)d_in[5];
  const float* bm    = (const float*)d_in[6];
  const float* Wo    = (const float*)d_in[7];
  const float* bo    = (const float*)d_in[8];
  const float* maddr = (const float*)d_in[9];
  const float* Wq    = (const float*)d_in[10];
  const float* bq    = (const float*)d_in[11];
  const float* us    = (const float*)d_in[12];
  const float* Wch   = (const float*)d_in[13];
  const float* Wci   = (const float*)d_in[14];
  u32* wsu  = (u32*)d_ws;
  float* out = (float*)d_out;

  hipFuncSetAttribute((const void*)dntm_step,
                      hipFuncAttributeMaxDynamicSharedMemorySize, 163840);

  pack_weights<<<56, 256, 0, stream>>>(Wi, Wh, Wm, Wq, Wch, Wci, maddr, Wo, wsu);
  dntm_step<<<32, 1024, SMEM_BYTES, stream>>>(batch, bi, bh, bm, bo, bq, us, wsu, out);
}

// Round 6
// 1342.071 us; speedup vs baseline: 1.0083x; 1.0083x over previous
//
#include <hip/hip_runtime.h>

typedef unsigned int u32;
typedef unsigned short u16;
typedef _Float16 f16x2 __attribute__((ext_vector_type(2)));

// ---------------- problem constants ----------------
// B=32, T=32, F=64, H=256, N=1024, A=64, C=192, M=256
// out: hs [32,256,32] (262144 f32) then outs [32,10,32] (10240 f32)

// ---------------- workspace (u32 offsets), all k4-packed uint4 [panel][k4][64] ----------------
#define WP_A0    0        // [Wh0;Wi0] 4 panels x 40 k4   (pairs: h 0..127, x 128..159)
#define WP_A1    40960
#define WP_A2H   81920    // Wh2 4 x 32
#define WP_A2I   114688   // Wi2 4 x 8
#define WP_AQ    122880   // Wq  4 x 32
#define WP_AC    155648   // [Wch;Wci] 3 x 40
#define WP_AM    186368   // Wm  12 x 32 (gate-major)
#define WP_AT2   284672   // maddr row-pairs: 16 panels x 8 k4 (outs n, k a)
#define WP_M4    317440   // maddr col view: [128 k4][64 a]  (outs a, k n-pairs)
#define WP_WO4   350208   // W_output: [10][32] uint4

// ---------------- LDS layout (f32 offsets) ----------------
#define SH_HX    0      // f32 h[256]
#define SH_H2    256    // u32[160] (h,x) f16 pairs
#define SH_Q     416    // f32 q[256] (incl bq)
#define SH_Q2    672    // u32[32]  q[0..63] f16 pairs
#define SH_GA0   704    // f32 [256]
#define SH_GA1   960    // f32 [256]
#define SH_GH2A  1216   // f32 [256]  Wh2 k-half 0
#define SH_GH2B  1472   // f32 [256]  Wh2 k-half 1
#define SH_GI2   1728   // f32 [256]
#define SH_GM    1984   // f32 [3][256]
#define SH_SIMA  2752   // f32 [1024]
#define SH_R2    3776   // u32 [128] reading f16 pairs
#define SH_D     3904   // f32 [32]
#define SH_G     3936   // f32 [32]
#define SH_RED   3968   // f32 [16]
#define SH_RED2  3984   // f32 [16]
#define SH_MISC  4000   // f32 [8]  [0]=beta
#define SH_B10   4008   // f32 [16]
#define SH_RA    4024   // f32 [8][64] reading_a partials
#define SH_CAND  4536   // u16[32*192] = 3072 f32 slots
#define SH_W     7608   // u16[32][1024] = 16384 f32 slots
#define SMEM_FLOATS 23992
#define SMEM_BYTES (SMEM_FLOATS*4)

#define WRED(v) { v += __shfl_xor(v,32); v += __shfl_xor(v,16); v += __shfl_xor(v,8); \
                  v += __shfl_xor(v,4);  v += __shfl_xor(v,2);  v += __shfl_xor(v,1); }

__device__ __forceinline__ f16x2 bch2(u32 u) { return __builtin_bit_cast(f16x2, u); }

#if __has_builtin(__builtin_amdgcn_fdot2)
__device__ __forceinline__ float FDOT2(u32 a, u32 b, float c) {
  return __builtin_amdgcn_fdot2(bch2(a), bch2(b), c, false);
}
#else
__device__ __forceinline__ float FDOT2(u32 a, u32 b, float c) {
  f16x2 x = bch2(a), y = bch2(b);
  return c + (float)x[0]*(float)y[0] + (float)x[1]*(float)y[1];
}
#endif

__device__ __forceinline__ u16 f2h(float x) {
  _Float16 h = (_Float16)x; return __builtin_bit_cast(u16, h);
}
__device__ __forceinline__ float h2f(u16 u) {
  return (float)__builtin_bit_cast(_Float16, u);
}
__device__ __forceinline__ u32 packh2(float lo, float hi) {
  return (u32)f2h(lo) | ((u32)f2h(hi) << 16);
}

// ---- k4-packed matvec: 1 out/lane, layout [k4][64] uint4.
// 4-k4 groups, 2-group lookahead software pipeline, all NAMED registers
// (bounded VGPR by construction, no arrays -> no scratch). NK4 % 4 == 0.
// Needs the 128-VGPR budget from amdgpu_waves_per_eu(4,4).
template<int NK4>
__device__ __forceinline__ float mv_os4(const u32* __restrict__ Wb,
                                        const u32* __restrict__ c2, const int ln)
{
  static_assert(NK4 % 4 == 0, "NK4 must be multiple of 4");
  constexpr int NG = NK4 / 4;
  const uint4* __restrict__ wp = (const uint4*)Wb + ln;
  const uint4* __restrict__ c4 = (const uint4*)c2;
  float a0 = 0.f, a1 = 0.f, a2 = 0.f, a3 = 0.f;
  uint4 wa0, wa1, wa2, wa3, ca0, ca1, ca2, ca3;
  uint4 wb0, wb1, wb2, wb3, cb0, cb1, cb2, cb3;
#define LWA_(g) { wa0 = wp[(g)*256]; wa1 = wp[(g)*256+64]; wa2 = wp[(g)*256+128]; wa3 = wp[(g)*256+192]; \
                  ca0 = c4[(g)*4];   ca1 = c4[(g)*4+1];    ca2 = c4[(g)*4+2];     ca3 = c4[(g)*4+3]; }
#define LWB_(g) { wb0 = wp[(g)*256]; wb1 = wp[(g)*256+64]; wb2 = wp[(g)*256+128]; wb3 = wp[(g)*256+192]; \
                  cb0 = c4[(g)*4];   cb1 = c4[(g)*4+1];    cb2 = c4[(g)*4+2];     cb3 = c4[(g)*4+3]; }
#define CMPA_ { a0=FDOT2(wa0.x,ca0.x,a0); a1=FDOT2(wa0.y,ca0.y,a1); a2=FDOT2(wa0.z,ca0.z,a2); a3=FDOT2(wa0.w,ca0.w,a3); \
                a0=FDOT2(wa1.x,ca1.x,a0); a1=FDOT2(wa1.y,ca1.y,a1); a2=FDOT2(wa1.z,ca1.z,a2); a3=FDOT2(wa1.w,ca1.w,a3); \
                a0=FDOT2(wa2.x,ca2.x,a0); a1=FDOT2(wa2.y,ca2.y,a1); a2=FDOT2(wa2.z,ca2.z,a2); a3=FDOT2(wa2.w,ca2.w,a3); \
                a0=FDOT2(wa3.x,ca3.x,a0); a1=FDOT2(wa3.y,ca3.y,a1); a2=FDOT2(wa3.z,ca3.z,a2); a3=FDOT2(wa3.w,ca3.w,a3); }
#define CMPB_ { a0=FDOT2(wb0.x,cb0.x,a0); a1=FDOT2(wb0.y,cb0.y,a1); a2=FDOT2(wb0.z,cb0.z,a2); a3=FDOT2(wb0.w,cb0.w,a3); \
                a0=FDOT2(wb1.x,cb1.x,a0); a1=FDOT2(wb1.y,cb1.y,a1); a2=FDOT2(wb1.z,cb1.z,a2); a3=FDOT2(wb1.w,cb1.w,a3); \
                a0=FDOT2(wb2.x,cb2.x,a0); a1=FDOT2(wb2.y,cb2.y,a1); a2=FDOT2(wb2.z,cb2.z,a2); a3=FDOT2(wb2.w,cb2.w,a3); \
                a0=FDOT2(wb3.x,cb3.x,a0); a1=FDOT2(wb3.y,cb3.y,a1); a2=FDOT2(wb3.z,cb3.z,a2); a3=FDOT2(wb3.w,cb3.w,a3); }
  LWA_(0);
  if constexpr (NG == 1) {
    CMPA_;
  } else {
    LWB_(1);
    #pragma unroll
    for (int g = 0; g + 2 < NG; ++g) {
      if ((g & 1) == 0) { CMPA_; LWA_(g + 2); }
      else              { CMPB_; LWB_(g + 2); }
    }
    if constexpr (((NG - 2) & 1) == 0) { CMPA_; CMPB_; }
    else                               { CMPB_; CMPA_; }
  }
#undef LWA_
#undef LWB_
#undef CMPA_
#undef CMPB_
  return (a0 + a1) + (a2 + a3);
}

// ---- dual-panel NK4=8 matvec: two 64-out panels over the SAME coef (shared c),
// one pipeline prologue, <=8 uint4 w-loads in flight. Returns (panel0, panel1).
__device__ __forceinline__ float2 mv2_os4_8(const u32* __restrict__ W0,
    const u32* __restrict__ W1, const u32* __restrict__ c2, const int ln)
{
  const uint4* __restrict__ w0p = (const uint4*)W0 + ln;
  const uint4* __restrict__ w1p = (const uint4*)W1 + ln;
  const uint4* __restrict__ c4 = (const uint4*)c2;
  float a0=0.f,a1=0.f,a2=0.f,a3=0.f, b0=0.f,b1=0.f,b2=0.f,b3=0.f;
  uint4 wa0=w0p[0],   wa1=w0p[64],  wa2=w0p[128], wa3=w0p[192];
  uint4 ca0=c4[0],    ca1=c4[1],    ca2=c4[2],    ca3=c4[3];
  uint4 wb0=w0p[256], wb1=w0p[320], wb2=w0p[384], wb3=w0p[448];
  uint4 cb0=c4[4],    cb1=c4[5],    cb2=c4[6],    cb3=c4[7];
  // P0 g0
  a0=FDOT2(wa0.x,ca0.x,a0); a1=FDOT2(wa0.y,ca0.y,a1); a2=FDOT2(wa0.z,ca0.z,a2); a3=FDOT2(wa0.w,ca0.w,a3);
  a0=FDOT2(wa1.x,ca1.x,a0); a1=FDOT2(wa1.y,ca1.y,a1); a2=FDOT2(wa1.z,ca1.z,a2); a3=FDOT2(wa1.w,ca1.w,a3);
  a0=FDOT2(wa2.x,ca2.x,a0); a1=FDOT2(wa2.y,ca2.y,a1); a2=FDOT2(wa2.z,ca2.z,a2); a3=FDOT2(wa2.w,ca2.w,a3);
  a0=FDOT2(wa3.x,ca3.x,a0); a1=FDOT2(wa3.y,ca3.y,a1); a2=FDOT2(wa3.z,ca3.z,a2); a3=FDOT2(wa3.w,ca3.w,a3);
  wa0=w1p[0]; wa1=w1p[64]; wa2=w1p[128]; wa3=w1p[192];     // P1 g0
  // P0 g1
  a0=FDOT2(wb0.x,cb0.x,a0); a1=FDOT2(wb0.y,cb0.y,a1); a2=FDOT2(wb0.z,cb0.z,a2); a3=FDOT2(wb0.w,cb0.w,a3);
  a0=FDOT2(wb1.x,cb1.x,a0); a1=FDOT2(wb1.y,cb1.y,a1); a2=FDOT2(wb1.z,cb1.z,a2); a3=FDOT2(wb1.w,cb1.w,a3);
  a0=FDOT2(wb2.x,cb2.x,a0); a1=FDOT2(wb2.y,cb2.y,a1); a2=FDOT2(wb2.z,cb2.z,a2); a3=FDOT2(wb2.w,cb2.w,a3);
  a0=FDOT2(wb3.x,cb3.x,a0); a1=FDOT2(wb3.y,cb3.y,a1); a2=FDOT2(wb3.z,cb3.z,a2); a3=FDOT2(wb3.w,cb3.w,a3);
  wb0=w1p[256]; wb1=w1p[320]; wb2=w1p[384]; wb3=w1p[448];  // P1 g1
  // P1 g0
  b0=FDOT2(wa0.x,ca0.x,b0); b1=FDOT2(wa0.y,ca0.y,b1); b2=FDOT2(wa0.z,ca0.z,b2); b3=FDOT2(wa0.w,ca0.w,b3);
  b0=FDOT2(wa1.x,ca1.x,b0); b1=FDOT2(wa1.y,ca1.y,b1); b2=FDOT2(wa1.z,ca1.z,b2); b3=FDOT2(wa1.w,ca1.w,b3);
  b0=FDOT2(wa2.x,ca2.x,b0); b1=FDOT2(wa2.y,ca2.y,b1); b2=FDOT2(wa2.z,ca2.z,b2); b3=FDOT2(wa2.w,ca2.w,b3);
  b0=FDOT2(wa3.x,ca3.x,b0); b1=FDOT2(wa3.y,ca3.y,b1); b2=FDOT2(wa3.z,ca3.z,b2); b3=FDOT2(wa3.w,ca3.w,b3);
  // P1 g1
  b0=FDOT2(wb0.x,cb0.x,b0); b1=FDOT2(wb0.y,cb0.y,b1); b2=FDOT2(wb0.z,cb0.z,b2); b3=FDOT2(wb0.w,cb0.w,b3);
  b0=FDOT2(wb1.x,cb1.x,b0); b1=FDOT2(wb1.y,cb1.y,b1); b2=FDOT2(wb1.z,cb1.z,b2); b3=FDOT2(wb1.w,cb1.w,b3);
  b0=FDOT2(wb2.x,cb2.x,b0); b1=FDOT2(wb2.y,cb2.y,b1); b2=FDOT2(wb2.z,cb2.z,b2); b3=FDOT2(wb2.w,cb2.w,b3);
  b0=FDOT2(wb3.x,cb3.x,b0); b1=FDOT2(wb3.y,cb3.y,b1); b2=FDOT2(wb3.z,cb3.z,b2); b3=FDOT2(wb3.w,cb3.w,b3);
  return make_float2((a0+a1)+(a2+a3), (b0+b1)+(b2+b3));
}

__device__ __forceinline__ void out_lse(const float* __restrict__ b10,
    float* __restrict__ out, const int t_out, const int bb, const int ln)
{
  float v = (ln < 10) ? b10[ln] : -1e30f;
  float m = v;
  m = fmaxf(m, __shfl_xor(m, 8, 16));
  m = fmaxf(m, __shfl_xor(m, 4, 16));
  m = fmaxf(m, __shfl_xor(m, 2, 16));
  m = fmaxf(m, __shfl_xor(m, 1, 16));
  float e = (ln < 10) ? __expf(v - m) : 0.f;
  float s = e;
  s += __shfl_xor(s, 8, 16);
  s += __shfl_xor(s, 4, 16);
  s += __shfl_xor(s, 2, 16);
  s += __shfl_xor(s, 1, 16);
  if (ln < 10) out[262144 + t_out * 320 + ln * 32 + bb] = v - m - logf(s);
}

// ---------------- pack kernel ----------------
__device__ __forceinline__ void pack_panel(const float* __restrict__ srcA, int KA, int np4A,
                                           const float* __restrict__ srcB, int KB,
                                           int np4tot, int o0, u32* __restrict__ dstu, int tid)
{
  uint4* d4 = (uint4*)dstu;
  for (int idx = tid; idx < np4tot * 64; idx += 256) {
    const int k4 = idx >> 6, o = idx & 63;
    const float* s = (k4 < np4A) ? (srcA + (size_t)(o0 + o) * KA + k4 * 8)
                                 : (srcB + (size_t)(o0 + o) * KB + (k4 - np4A) * 8);
    uint4 v;
    v.x = packh2(s[0], s[1]); v.y = packh2(s[2], s[3]);
    v.z = packh2(s[4], s[5]); v.w = packh2(s[6], s[7]);
    d4[idx] = v;
  }
}

__global__ void pack_weights(const float* __restrict__ Wi, const float* __restrict__ Wh,
                             const float* __restrict__ Wm, const float* __restrict__ Wq,
                             const float* __restrict__ Wch, const float* __restrict__ Wci,
                             const float* __restrict__ maddr, const float* __restrict__ Wo,
                             u32* __restrict__ wsu)
{
  const int b = blockIdx.x, tid = threadIdx.x;
  if (b < 4)        pack_panel(Wh,          256, 32, Wi,        64, 40, b*64,      wsu + WP_A0  + b*10240, tid);
  else if (b < 8)   pack_panel(Wh + 65536,  256, 32, Wi + 16384,64, 40, (b-4)*64,  wsu + WP_A1  + (b-4)*10240, tid);
  else if (b < 12)  pack_panel(Wh + 131072, 256, 32, Wh,       256, 32, (b-8)*64,  wsu + WP_A2H + (b-8)*8192, tid);
  else if (b < 16)  pack_panel(Wi + 32768,   64,  8, Wi,        64,  8, (b-12)*64, wsu + WP_A2I + (b-12)*2048, tid);
  else if (b < 20)  pack_panel(Wq,          256, 32, Wq,       256, 32, (b-16)*64, wsu + WP_AQ  + (b-16)*8192, tid);
  else if (b < 23)  pack_panel(Wch,         256, 32, Wci,       64, 40, (b-20)*64, wsu + WP_AC  + (b-20)*10240, tid);
  else if (b < 35) { int x = b-23; int g = x>>2;
                    pack_panel(Wm + g*65536, 256, 32, Wm,      256, 32, (x&3)*64,  wsu + WP_AM  + x*8192, tid); }
  else if (b < 51)  pack_panel(maddr,        64,  8, maddr,     64,  8, (b-35)*64, wsu + WP_AT2 + (b-35)*2048, tid);
  else if (b < 55) { // M4: uint4(k4, a) = n-pairs 4k4..4k4+3 of maddr column a
    const int kb = b - 51;
    uint4* d4 = (uint4*)(wsu + WP_M4);
    for (int idx = tid; idx < 2048; idx += 256) {
      const int k4 = kb*32 + (idx >> 6), a = idx & 63;
      const float* s = maddr + (size_t)(8*k4)*64 + a;
      uint4 v;
      v.x = packh2(s[0],   s[64]);  v.y = packh2(s[128], s[192]);
      v.z = packh2(s[256], s[320]); v.w = packh2(s[384], s[448]);
      d4[k4*64 + a] = v;
    }
  } else {          // WO4: [10][32] uint4 = pack8(Wo[j][8l..8l+8])
    uint4* d4 = (uint4*)(wsu + WP_WO4);
    for (int idx = tid; idx < 320; idx += 256) {
      const int j = idx >> 5, l = idx & 31;
      const float* s = Wo + j*256 + l*8;
      uint4 v;
      v.x = packh2(s[0], s[1]); v.y = packh2(s[2], s[3]);
      v.z = packh2(s[4], s[5]); v.w = packh2(s[6], s[7]);
      d4[idx] = v;
    }
  }
}

// ---------------- main persistent per-batch kernel ----------------
// amdgpu_waves_per_eu(4,4): pin occupancy target to exactly 4 waves/SIMD
// (16-wave block, 1 block/CU by LDS) -> VGPR budget 512/4 = 128, so the
// 16-uint4 software pipeline stays in registers (round-5 spilled at 64).
__global__ __launch_bounds__(1024)
__attribute__((amdgpu_waves_per_eu(4, 4)))
void dntm_step(
    const float* __restrict__ batch, const float* __restrict__ bi,
    const float* __restrict__ bh, const float* __restrict__ bm,
    const float* __restrict__ bo, const float* __restrict__ bq,
    const float* __restrict__ usharp, const u32* __restrict__ wsu,
    float* __restrict__ out)
{
  extern __shared__ float sm[];
  u32* h2u   = (u32*)(sm + SH_H2);
  u32* Q2u   = (u32*)(sm + SH_Q2);
  u32* R2u   = (u32*)(sm + SH_R2);
  u16* candh = (u16*)(sm + SH_CAND);
  u16* SW16  = (u16*)(sm + SH_W);
  u32* SW32  = (u32*)(sm + SH_W);
  const int tid = threadIdx.x, ln = tid & 63, wv = tid >> 6;
  const int bb = blockIdx.x;

  if (tid < 256) sm[SH_HX + tid] = 0.f;
  if (tid < 128) h2u[tid] = 0u;
  if (tid >= 128 && tid < 160) {
    const int j = tid - 128;
    const int i0 = (2*j)*32 + bb, i1 = i0 + 32;
    const float x0 = batch[(i0 >> 6)*2048 + (i0 & 63)];
    const float x1 = batch[(i1 >> 6)*2048 + (i1 & 63)];
    h2u[128 + j] = packh2(x0, x1);
  }
  __syncthreads();

  for (int t = 0; t < 32; ++t) {
    // ===== P1: all h/x matvecs (f16 dot2), balanced ~40-56 k4 per wave =====
    if (wv < 8) {
      if (wv < 4) {
        sm[SH_GA0 + wv*64 + ln] = mv_os4<40>(wsu + WP_A0 + wv*10240, h2u, ln);
      } else {
        sm[SH_GA1 + (wv-4)*64 + ln] = mv_os4<40>(wsu + WP_A1 + (wv-4)*10240, h2u, ln);
      }
      // Wh2 half-panel: half index = wv (panel wv>>1, k-part wv&1)
      const int p = wv >> 1, pt = wv & 1;
      const float hv = mv_os4<16>(wsu + WP_A2H + p*8192 + pt*4096, h2u + pt*64, ln);
      sm[(pt ? SH_GH2B : SH_GH2A) + p*64 + ln] = hv;
    } else if (wv < 11) {
      const int p = wv - 8;
      const float cv = mv_os4<40>(wsu + WP_AC + p*10240, h2u, ln);
      candh[t*192 + p*64 + ln] = f2h(fmaxf(cv, 0.f));
    } else if (wv == 11) {
      const float2 r01 = mv2_os4_8(wsu+WP_A2I,        wsu+WP_A2I+2048, h2u+128, ln);
      const float2 r23 = mv2_os4_8(wsu+WP_A2I+4096,   wsu+WP_A2I+6144, h2u+128, ln);
      sm[SH_GI2 +       ln] = r01.x; sm[SH_GI2 +  64 + ln] = r01.y;
      sm[SH_GI2 + 128 + ln] = r23.x; sm[SH_GI2 + 192 + ln] = r23.y;
      { // beta = softplus(u.h) + 1  (f32)
        const float4 h4 = *(const float4*)(sm + SH_HX + ln*4);
        const float4 u4 = *(const float4*)(usharp + ln*4);
        float v = h4.x*u4.x + h4.y*u4.y + h4.z*u4.z + h4.w*u4.w;
        WRED(v);
        if (!ln) sm[SH_MISC] = fmaxf(v, 0.f) + log1pf(expf(-fabsf(v))) + 1.f;
      }
    } else {
      const int p = wv - 12;
      const float qv = mv_os4<32>(wsu + WP_AQ + p*8192, h2u, ln) + bq[p*64 + ln];
      sm[SH_Q + p*64 + ln] = qv;
      if (wv == 12) {
        const float qh = __shfl_down(qv, 1);
        if (!(ln & 1)) Q2u[ln >> 1] = packh2(qv, qh);
      }
      if (wv == 13 && t > 0) { // logits of h_t == h_new(t-1), f16 Wo x f16 h pairs
        const uint4 ch = ((const uint4*)h2u)[ln & 31];
        const uint4* wo4 = (const uint4*)(wsu + WP_WO4);
        for (int j = 0; j < 10; ++j) {
          float lv = 0.f;
          if (ln < 32) {
            const uint4 w4 = wo4[j*32 + ln];
            lv = FDOT2(w4.x, ch.x, lv); lv = FDOT2(w4.y, ch.y, lv);
            lv = FDOT2(w4.z, ch.z, lv); lv = FDOT2(w4.w, ch.w, lv);
          }
          WRED(lv);
          if (!ln) sm[SH_B10 + j] = lv + bo[j];
        }
      }
    }
    __syncthreads();

    // ===== P2: sim addr-part (dual-panel f16 dot2); d[s] = cand_s . q_c; out_lse(t-1) =====
    if (wv < 8) {
      const float2 r = mv2_os4_8(wsu + WP_AT2 + (2*wv)*2048,
                                 wsu + WP_AT2 + (2*wv+1)*2048, Q2u, ln);
      sm[SH_SIMA + wv*128 + ln]      = r.x;
      sm[SH_SIMA + wv*128 + 64 + ln] = r.y;
    } else if (wv < 15) {
      const float q0 = sm[SH_Q + 64 + ln], q1 = sm[SH_Q + 128 + ln], q2 = sm[SH_Q + 192 + ln];
      for (int s = wv - 8; s < t; s += 7) {
        float a2 = h2f(candh[s*192 + ln]) * q0
                 + h2f(candh[s*192 + 64 + ln]) * q1
                 + h2f(candh[s*192 + 128 + ln]) * q2;
        WRED(a2);
        if (!ln) sm[SH_D + s] = a2;
      }
    } else {
      if (t > 0) out_lse(sm + SH_B10, out, t - 1, bb, ln);
    }
    __syncthreads();

    // ===== P3: v = beta*(sim_a + sum_s d[s] w_s[n]); wave max =====
    const int n3 = wv * 64 + ln;
    float v = sm[SH_SIMA + n3];
    #pragma unroll 4
    for (int s = 0; s < t; ++s) v = fmaf(sm[SH_D + s], h2f(SW16[s*1024 + n3]), v);
    v *= sm[SH_MISC];
    {
      float mx = v;
      mx = fmaxf(mx, __shfl_xor(mx, 32)); mx = fmaxf(mx, __shfl_xor(mx, 16));
      mx = fmaxf(mx, __shfl_xor(mx, 8));  mx = fmaxf(mx, __shfl_xor(mx, 4));
      mx = fmaxf(mx, __shfl_xor(mx, 2));  mx = fmaxf(mx, __shfl_xor(mx, 1));
      if (!ln) sm[SH_RED + wv] = mx;
    }
    __syncthreads();

    // ===== P4: e = exp(v - gmax) -> f16 history row t (unnormalized); wave sums =====
    {
      float gmx = sm[SH_RED];
      #pragma unroll
      for (int i = 1; i < 16; ++i) gmx = fmaxf(gmx, sm[SH_RED + i]);
      const float e = __expf(v - gmx);
      SW16[t*1024 + n3] = f2h(e);
      float s2 = e; WRED(s2);
      if (!ln) sm[SH_RED2 + wv] = s2;
    }
    __syncthreads();

    // ===== P5: reading_a partials (M4 k4-packed); g[s] = w_s . w_t =====
    {
      float tot = 0.f;
      #pragma unroll
      for (int i = 0; i < 16; ++i) tot += sm[SH_RED2 + i];
      const float inv = 1.0f / tot;
      if (wv < 8) {
        const float acc = mv_os4<16>(wsu + WP_M4 + wv*16*256,
                                     SW32 + t*512 + wv*64, ln);
        sm[SH_RA + wv*64 + ln] = acc * inv;
      } else {
        const uint4 ea = ((const uint4*)(SW32 + t*512))[ln*2];
        const uint4 eb = ((const uint4*)(SW32 + t*512))[ln*2 + 1];
        for (int s = wv - 8; s < t; s += 8) {
          const uint4 wa = ((const uint4*)(SW32 + s*512))[ln*2];
          const uint4 wb = ((const uint4*)(SW32 + s*512))[ln*2 + 1];
          float a2 = 0.f;
          a2 = FDOT2(ea.x, wa.x, a2); a2 = FDOT2(ea.y, wa.y, a2);
          a2 = FDOT2(ea.z, wa.z, a2); a2 = FDOT2(ea.w, wa.w, a2);
          a2 = FDOT2(eb.x, wb.x, a2); a2 = FDOT2(eb.y, wb.y, a2);
          a2 = FDOT2(eb.z, wb.z, a2); a2 = FDOT2(eb.w, wb.w, a2);
          WRED(a2);
          if (!ln) sm[SH_G + s] = a2 * inv;
        }
      }
    }
    __syncthreads();

    // ===== P6: assemble reading -> f16 pairs R2 =====
    if (wv == 0) {
      float r = 0.f;
      #pragma unroll
      for (int j = 0; j < 8; ++j) r += sm[SH_RA + j*64 + ln];
      const float rh = __shfl_down(r, 1);
      if (!(ln & 1)) R2u[ln >> 1] = packh2(r, rh);
    } else if (wv < 4) {
      const int c = (wv - 1)*64 + ln;
      float r = 0.f;
      for (int s = 0; s < t; ++s) r = fmaf(h2f(candh[s*192 + c]), sm[SH_G + s], r);
      const float rh = __shfl_down(r, 1);
      if (!(ln & 1)) R2u[wv*32 + (ln >> 1)] = packh2(r, rh);
    }
    __syncthreads();

    // ===== P7: gm = Wm @ reading (12 waves, full K); normalize w row; prefetch x =====
    if (wv < 12) {
      const int g = wv >> 2, p = wv & 3;
      sm[SH_GM + g*256 + p*64 + ln] = mv_os4<32>(wsu + WP_AM + wv*8192, R2u, ln);
    } else if (wv < 14) {
      float tot = 0.f;
      #pragma unroll
      for (int i = 0; i < 16; ++i) tot += sm[SH_RED2 + i];
      const float inv = 1.0f / tot;
      u32* p = SW32 + t*512 + (wv - 12)*256 + ln*4;
      uint4 v4 = *(const uint4*)p;
      v4.x = packh2(h2f(v4.x & 0xffff)*inv, h2f(v4.x >> 16)*inv);
      v4.y = packh2(h2f(v4.y & 0xffff)*inv, h2f(v4.y >> 16)*inv);
      v4.z = packh2(h2f(v4.z & 0xffff)*inv, h2f(v4.z >> 16)*inv);
      v4.w = packh2(h2f(v4.w & 0xffff)*inv, h2f(v4.w >> 16)*inv);
      *(uint4*)p = v4;
    } else if (wv == 14) {
      if (t < 31 && ln < 32) {
        const int i0 = (2*ln)*32 + bb, i1 = i0 + 32;
        const float x0 = batch[(i0 >> 6)*2048 + (t+1)*64 + (i0 & 63)];
        const float x1 = batch[(i1 >> 6)*2048 + (t+1)*64 + (i1 & 63)];
        h2u[128 + ln] = packh2(x0, x1);
      }
    }
    __syncthreads();

    // ===== P8: gate combine, h update, hs output, pack h pairs =====
    if (tid < 256) {
      const int h = tid;
      const float g0  = sm[SH_GA0 + h] + bi[h]       + bh[h]       + sm[SH_GM + h]       + bm[h];
      const float g1  = sm[SH_GA1 + h] + bi[256 + h] + bh[256 + h] + sm[SH_GM + 256 + h] + bm[256 + h];
      const float gh2v = sm[SH_GH2A + h] + sm[SH_GH2B + h] + bh[512 + h];
      const float gi2v = sm[SH_GI2 + h] + bi[512 + h];
      const float gm2  = sm[SH_GM + 512 + h] + bm[512 + h];
      const float r = 1.f / (1.f + __expf(-g0));
      const float z = 1.f / (1.f + __expf(-g1));
      const float nn = tanhf(gi2v + gm2 + r * gh2v);
      const float hn = (1.f - z) * nn + z * sm[SH_HX + h];
      sm[SH_HX + h] = hn;
      out[t*8192 + h*32 + bb] = hn;
      const float hn1 = __shfl_down(hn, 1);
      if (!(tid & 1)) h2u[tid >> 1] = packh2(hn, hn1);
    }
    __syncthreads();
  }

  // ---- epilogue: out[31] ----
  if (wv == 0) {
    const uint4 ch = ((const uint4*)h2u)[ln & 31];
    const uint4* wo4 = (const uint4*)(wsu + WP_WO4);
    for (int j = 0; j < 10; ++j) {
      float lv = 0.f;
      if (ln < 32) {
        const uint4 w4 = wo4[j*32 + ln];
        lv = FDOT2(w4.x, ch.x, lv); lv = FDOT2(w4.y, ch.y, lv);
        lv = FDOT2(w4.z, ch.z, lv); lv = FDOT2(w4.w, ch.w, lv);
      }
      WRED(lv);
      if (!ln) sm[SH_B10 + j] = lv + bo[j];
    }
    out_lse(sm + SH_B10, out, 31, bb, ln);
  }
}

extern "C" void kernel_launch(void* const* d_in, const int* in_sizes, int n_in,
                              void* d_out, int out_size, void* d_ws, size_t ws_size,
                              hipStream_t stream) {
  (void)in_sizes; (void)n_in; (void)out_size; (void)ws_size;
  const float* batch = (const float*)d_in[0];
  const float* Wi    = (const float*)d_in[1];
  const float* bi    = (const float*)d_in[2];
  const float* Wh    = (const float*)d_in[3];
  const float* bh    = (const float*)d_in[4];
  const float* Wm    = (const float*)d_in[5];
  const float* bm    = (const float*)d_in[6];
  const float* Wo    = (const float*)d_in[7];
  const float* bo    = (const float*)d_in[8];
  const float* maddr = (const float*)d_in[9];
  const float* Wq    = (const float*)d_in[10];
  const float* bq    = (const float*)d_in[11];
  const float* us    = (const float*)d_in[12];
  const float* Wch   = (const float*)d_in[13];
  const float* Wci   = (const float*)d_in[14];
  u32* wsu  = (u32*)d_ws;
  float* out = (float*)d_out;

  hipFuncSetAttribute((const void*)dntm_step,
                      hipFuncAttributeMaxDynamicSharedMemorySize, 163840);

  pack_weights<<<56, 256, 0, stream>>>(Wi, Wh, Wm, Wq, Wch, Wci, maddr, Wo, wsu);
  dntm_step<<<32, 1024, SMEM_BYTES, stream>>>(batch, bi, bh, bm, bo, bq, us, wsu, out);
}

// Round 7
// 934.366 us; speedup vs baseline: 1.4482x; 1.4363x over previous
//
#include <hip/hip_runtime.h>

typedef unsigned int u32;
typedef unsigned short u16;
typedef _Float16 f16x2 __attribute__((ext_vector_type(2)));

// ---------------- problem constants ----------------
// B=32, T=32, F=64, H=256, N=1024, A=64, C=192, M=256
// out: hs [32,256,32] (262144 f32) then outs [32,10,32] (10240 f32)

// ---------------- workspace (u32 offsets): int8 k16-chunk panels [k16][64] uint4 ----
#define WP_A0    0        // [Wh0;Wi0] 4 panels x 20 chunks (k: h 0..255, x 256..319)
#define WP_A1    20480
#define WP_A2H   40960    // Wh2 4 x 16
#define WP_A2I   57344    // Wi2 4 x 4
#define WP_AQ    61440    // Wq  4 x 16
#define WP_AC    77824    // [Wch;Wci] 3 x 20
#define WP_AM    93184    // Wm 12 x 16 (gate-major)
#define WP_AT2   142336   // maddr rows: 16 panels x 4 (outs n, k a)
#define WP_M4    158720   // maddr cols: 1 panel 64 chunks (outs a, k n)
#define WP_WO4   175104   // W_output f16: [10][32] uint4
#define WP_SC    176384   // float2 scales: per panel-column (s, k2)

// scale bases (float2 index)
#define SC_A0   0
#define SC_A1   256
#define SC_A2H  512
#define SC_A2I  768
#define SC_AQ   1024
#define SC_AC   1280
#define SC_AM   1472
#define SC_AT2  2240
#define SC_M4   3264

// ---------------- LDS layout (f32 offsets) ----------------
#define SH_HX    0      // f32 h[256]
#define SH_H2    256    // u32[160] (h,x) f16 pairs
#define SH_Q     416    // f32 q[256] (incl bq)
#define SH_Q2    672    // u32[32] q[0..63] f16 pairs
#define SH_GA0   704    // f32 [256]
#define SH_GA1   960    // f32 [256]
#define SH_GH2   1216   // f32 [256]
#define SH_GI2   1472   // f32 [256]
#define SH_GM    1728   // f32 [3][256]
#define SH_SIMA  2496   // f32 [1024]
#define SH_R2    3520   // u32 [128] reading f16 pairs
#define SH_D     3648   // f32 [32]
#define SH_G     3680   // f32 [32]
#define SH_RED   3712   // f32 [16]
#define SH_RED2  3728   // f32 [16]
#define SH_MISC  3744   // f32 [8]  [0]=beta
#define SH_B10   3752   // f32 [16]
#define SH_RA    3768   // f32 [8][64] reading_a raw partials
#define SH_CAND  4280   // u16[32*192] = 3072 f32 slots
#define SH_W     7352   // u16[32][1024] = 16384 f32 slots
#define SMEM_FLOATS 23736
#define SMEM_BYTES (SMEM_FLOATS*4)

#define WRED(v) { v += __shfl_xor(v,32); v += __shfl_xor(v,16); v += __shfl_xor(v,8); \
                  v += __shfl_xor(v,4);  v += __shfl_xor(v,2);  v += __shfl_xor(v,1); }

__device__ __forceinline__ f16x2 bch2(u32 u) { return __builtin_bit_cast(f16x2, u); }

#if __has_builtin(__builtin_amdgcn_fdot2)
__device__ __forceinline__ float FDOT2(u32 a, u32 b, float c) {
  return __builtin_amdgcn_fdot2(bch2(a), bch2(b), c, false);
}
#else
__device__ __forceinline__ float FDOT2(u32 a, u32 b, float c) {
  f16x2 x = bch2(a), y = bch2(b);
  return c + (float)x[0]*(float)y[0] + (float)x[1]*(float)y[1];
}
#endif

__device__ __forceinline__ u16 f2h(float x) {
  _Float16 h = (_Float16)x; return __builtin_bit_cast(u16, h);
}
__device__ __forceinline__ float h2f(u16 u) {
  return (float)__builtin_bit_cast(_Float16, u);
}
__device__ __forceinline__ u32 packh2(float lo, float hi) {
  return (u32)f2h(lo) | ((u32)f2h(hi) << 16);
}

#define ONE2 0x3C003C00u  // (1.0h, 1.0h)

// bytes j,j+1 of w -> f16 pair (1024+b_j, 1024+b_{j+1}). J in {0,2}.
template<int J>
__device__ __forceinline__ u32 mkpair(u32 w) {
#if __has_builtin(__builtin_amdgcn_perm)
  const u32 sel = (J == 0) ? 0x0C010C00u : 0x0C030C02u;
  return __builtin_amdgcn_perm(w, w, sel) | 0x64006400u;
#else
  return (((w >> (8*J)) & 0xFFu) | (((w >> (8*J + 8)) & 0xFFu) << 16)) | 0x64006400u;
#endif
}

// ---- int8 matvec, 1 out/lane. Wb: [k16][64] uint4 (16 int8-biased weights/lane-load).
// c: f16 pairs in LDS. Depth-4 load pipeline; constant-indexed w[4] -> registers.
// MODE 0: return s*dotq + k2*sumc (scale[ln]) ; MODE 1: return dotq - 1024*sumc (raw Σb·c).
template<int NK16, int MODE>
__device__ __forceinline__ float mv_u8(const u32* __restrict__ Wb,
    const u32* __restrict__ c2, const float2* __restrict__ scale, const int ln)
{
  const uint4* __restrict__ wp = (const uint4*)Wb + ln;
  const uint4* __restrict__ c4 = (const uint4*)c2;
  uint4 w[4];
  #pragma unroll
  for (int i = 0; i < 4; ++i) if (i < NK16) w[i] = wp[i*64];
  float a0 = 0.f, a1 = 0.f, a2 = 0.f, a3 = 0.f, s0 = 0.f, s1 = 0.f;
  #pragma unroll
  for (int i = 0; i < NK16; ++i) {
    const uint4 cw0 = c4[2*i], cw1 = c4[2*i + 1];
    const uint4 ww = w[i & 3];
    if (i + 4 < NK16) w[i & 3] = wp[(i + 4)*64];
    a0 = FDOT2(mkpair<0>(ww.x), cw0.x, a0);
    a1 = FDOT2(mkpair<2>(ww.x), cw0.y, a1);
    a2 = FDOT2(mkpair<0>(ww.y), cw0.z, a2);
    a3 = FDOT2(mkpair<2>(ww.y), cw0.w, a3);
    a0 = FDOT2(mkpair<0>(ww.z), cw1.x, a0);
    a1 = FDOT2(mkpair<2>(ww.z), cw1.y, a1);
    a2 = FDOT2(mkpair<0>(ww.w), cw1.z, a2);
    a3 = FDOT2(mkpair<2>(ww.w), cw1.w, a3);
    s0 = FDOT2(cw0.x, ONE2, s0); s1 = FDOT2(cw0.y, ONE2, s1);
    s0 = FDOT2(cw0.z, ONE2, s0); s1 = FDOT2(cw0.w, ONE2, s1);
    s0 = FDOT2(cw1.x, ONE2, s0); s1 = FDOT2(cw1.y, ONE2, s1);
    s0 = FDOT2(cw1.z, ONE2, s0); s1 = FDOT2(cw1.w, ONE2, s1);
  }
  const float dotq = (a0 + a1) + (a2 + a3);
  const float sumc = s0 + s1;
  if (MODE == 1) return dotq - 1024.0f*sumc;
  const float2 sc = scale[ln];
  return sc.x*dotq + sc.y*sumc;
}

__device__ __forceinline__ void out_lse(const float* __restrict__ b10,
    float* __restrict__ out, const int t_out, const int bb, const int ln)
{
  float v = (ln < 10) ? b10[ln] : -1e30f;
  float m = v;
  m = fmaxf(m, __shfl_xor(m, 8, 16));
  m = fmaxf(m, __shfl_xor(m, 4, 16));
  m = fmaxf(m, __shfl_xor(m, 2, 16));
  m = fmaxf(m, __shfl_xor(m, 1, 16));
  float e = (ln < 10) ? __expf(v - m) : 0.f;
  float s = e;
  s += __shfl_xor(s, 8, 16);
  s += __shfl_xor(s, 4, 16);
  s += __shfl_xor(s, 2, 16);
  s += __shfl_xor(s, 1, 16);
  if (ln < 10) out[262144 + t_out * 320 + ln * 32 + bb] = v - m - logf(s);
}

// ---------------- pack kernel: int8 quantization, per-column (s, k2) ----------------
__global__ void pack_weights(const float* __restrict__ Wi, const float* __restrict__ Wh,
                             const float* __restrict__ Wm, const float* __restrict__ Wq,
                             const float* __restrict__ Wch, const float* __restrict__ Wci,
                             const float* __restrict__ maddr, const float* __restrict__ Wo,
                             u32* __restrict__ wsu)
{
  const int b = blockIdx.x, tid = threadIdx.x;
  if (b == 52) {  // WO4 f16: [10][32] uint4 = pack8(Wo[j][8l..8l+8])
    uint4* d4 = (uint4*)(wsu + WP_WO4);
    for (int idx = tid; idx < 320; idx += 256) {
      const int j = idx >> 5, l = idx & 31;
      const float* s = Wo + j*256 + l*8;
      uint4 v;
      v.x = packh2(s[0], s[1]); v.y = packh2(s[2], s[3]);
      v.z = packh2(s[4], s[5]); v.w = packh2(s[6], s[7]);
      d4[idx] = v;
    }
    return;
  }
  const float *srcA = nullptr, *srcB = nullptr;
  int KA = 0, KB = 0, Ktot = 0, o0 = 0, scb = 0;
  u32* dst = nullptr; bool colmode = false, m4mode = false;
  if (b < 4)       { srcA=Wh;         KA=256; srcB=Wi;         KB=64; Ktot=320; o0=b*64;
                     dst=wsu+WP_A0 + b*5120;       scb=SC_A0  + b*64; }
  else if (b < 8)  { srcA=Wh+65536;   KA=256; srcB=Wi+16384;   KB=64; Ktot=320; o0=(b-4)*64;
                     dst=wsu+WP_A1 + (b-4)*5120;   scb=SC_A1  + (b-4)*64; }
  else if (b < 12) { srcA=Wh+131072;  KA=256; Ktot=256; o0=(b-8)*64;
                     dst=wsu+WP_A2H + (b-8)*4096;  scb=SC_A2H + (b-8)*64; }
  else if (b < 16) { srcA=Wi+32768;   KA=64;  Ktot=64;  o0=(b-12)*64;
                     dst=wsu+WP_A2I + (b-12)*1024; scb=SC_A2I + (b-12)*64; }
  else if (b < 20) { srcA=Wq;         KA=256; Ktot=256; o0=(b-16)*64;
                     dst=wsu+WP_AQ + (b-16)*4096;  scb=SC_AQ  + (b-16)*64; }
  else if (b < 23) { srcA=Wch;        KA=256; srcB=Wci;        KB=64; Ktot=320; o0=(b-20)*64;
                     dst=wsu+WP_AC + (b-20)*5120;  scb=SC_AC  + (b-20)*64; }
  else if (b < 35) { const int x = b-23;
                     srcA=Wm + (x>>2)*65536; KA=256; Ktot=256; o0=(x&3)*64;
                     dst=wsu+WP_AM + x*4096;       scb=SC_AM  + x*64; }
  else if (b < 51) { srcA=maddr;      KA=64;  Ktot=64;  o0=(b-35)*64;
                     dst=wsu+WP_AT2 + (b-35)*1024; scb=SC_AT2 + (b-35)*64; }
  else             { srcA=maddr;      KA=1024; Ktot=1024; o0=0; colmode=true; m4mode=true;
                     dst=wsu+WP_M4;                scb=SC_M4; }

  const int o = tid & 63, q = tid >> 6;
  const int kq = Ktot >> 2;
  float mn = 3e38f, mx = -3e38f;
  for (int k = q*kq; k < (q+1)*kq; ++k) {
    const float v = colmode ? srcA[(size_t)k*64 + o]
                  : ((k < KA) ? srcA[(size_t)(o0+o)*KA + k]
                              : srcB[(size_t)(o0+o)*KB + (k - KA)]);
    mn = fminf(mn, v); mx = fmaxf(mx, v);
  }
  __shared__ float smn[4][64], smx[4][64], sS[64], sMu[64];
  smn[q][o] = mn; smx[q][o] = mx;
  __syncthreads();
  if (tid < 64) {
    mn = fminf(fminf(smn[0][tid], smn[1][tid]), fminf(smn[2][tid], smn[3][tid]));
    mx = fmaxf(fmaxf(smx[0][tid], smx[1][tid]), fmaxf(smx[2][tid], smx[3][tid]));
    const float s = fmaxf((mx - mn)*(1.0f/255.0f), 1e-20f);
    const float mu = 0.5f*(mx + mn);
    sS[tid] = s; sMu[tid] = mu;
    float2* scp = (float2*)(wsu + WP_SC) + scb + tid;
    *scp = make_float2(s, m4mode ? (128.0f*s - mu) : (mu - 1152.0f*s));
  }
  __syncthreads();
  const float s = sS[o], mu = sMu[o], rs = 1.0f/s;
  uint4* d4 = (uint4*)dst;
  for (int cc = q*(kq >> 4); cc < (q+1)*(kq >> 4); ++cc) {
    u32 wd0 = 0, wd1 = 0, wd2 = 0, wd3 = 0;
    #pragma unroll
    for (int j = 0; j < 16; ++j) {
      const int k = cc*16 + j;
      const float v = colmode ? srcA[(size_t)k*64 + o]
                    : ((k < KA) ? srcA[(size_t)(o0+o)*KA + k]
                                : srcB[(size_t)(o0+o)*KB + (k - KA)]);
      const u32 bq8 = (u32)(int)fminf(fmaxf(rintf((v - mu)*rs) + 128.0f, 0.0f), 255.0f);
      const u32 sh = (u32)((j & 3)*8);
      if (j < 4) wd0 |= bq8 << sh; else if (j < 8) wd1 |= bq8 << sh;
      else if (j < 12) wd2 |= bq8 << sh; else wd3 |= bq8 << sh;
    }
    d4[cc*64 + o] = make_uint4(wd0, wd1, wd2, wd3);
  }
}

// ---------------- main persistent per-batch kernel ----------------
__global__ __launch_bounds__(1024) void dntm_step(
    const float* __restrict__ batch, const float* __restrict__ bi,
    const float* __restrict__ bh, const float* __restrict__ bm,
    const float* __restrict__ bo, const float* __restrict__ bq,
    const float* __restrict__ usharp, const u32* __restrict__ wsu,
    float* __restrict__ out)
{
  extern __shared__ float sm[];
  u32* h2u   = (u32*)(sm + SH_H2);
  u32* Q2u   = (u32*)(sm + SH_Q2);
  u32* R2u   = (u32*)(sm + SH_R2);
  u16* candh = (u16*)(sm + SH_CAND);
  u16* SW16  = (u16*)(sm + SH_W);
  u32* SW32  = (u32*)(sm + SH_W);
  const float2* SC = (const float2*)(wsu + WP_SC);
  const int tid = threadIdx.x, ln = tid & 63, wv = tid >> 6;
  const int bb = blockIdx.x;

  if (tid < 256) sm[SH_HX + tid] = 0.f;
  if (tid < 128) h2u[tid] = 0u;
  if (tid >= 128 && tid < 160) {
    const int j = tid - 128;
    const int i0 = (2*j)*32 + bb, i1 = i0 + 32;
    const float x0 = batch[(i0 >> 6)*2048 + (i0 & 63)];
    const float x1 = batch[(i1 >> 6)*2048 + (i1 & 63)];
    h2u[128 + j] = packh2(x0, x1);
  }
  __syncthreads();

  for (int t = 0; t < 32; ++t) {
    // ===== P1: h/x matvecs (int8 w, f16 c) =====
    if (wv < 4) {
      sm[SH_GA0 + wv*64 + ln] = mv_u8<20,0>(wsu + WP_A0 + wv*5120, h2u, SC + SC_A0 + wv*64, ln);
    } else if (wv < 8) {
      const int p = wv - 4;
      sm[SH_GA1 + p*64 + ln] = mv_u8<20,0>(wsu + WP_A1 + p*5120, h2u, SC + SC_A1 + p*64, ln);
    } else if (wv < 12) {
      const int p = wv - 8;
      sm[SH_GH2 + p*64 + ln] = mv_u8<16,0>(wsu + WP_A2H + p*4096, h2u, SC + SC_A2H + p*64, ln);
      sm[SH_GI2 + p*64 + ln] = mv_u8<4,0>(wsu + WP_A2I + p*1024, h2u + 128, SC + SC_A2I + p*64, ln);
    } else {
      const int p = wv - 12;
      const float qv = mv_u8<16,0>(wsu + WP_AQ + p*4096, h2u, SC + SC_AQ + p*64, ln) + bq[p*64 + ln];
      sm[SH_Q + p*64 + ln] = qv;
      if (wv == 12) {
        const float qh = __shfl_down(qv, 1);
        if (!(ln & 1)) Q2u[ln >> 1] = packh2(qv, qh);
        // beta = softplus(u.h) + 1
        const float4 h4 = *(const float4*)(sm + SH_HX + ln*4);
        const float4 u4 = *(const float4*)(usharp + ln*4);
        float v = h4.x*u4.x + h4.y*u4.y + h4.z*u4.z + h4.w*u4.w;
        WRED(v);
        if (!ln) sm[SH_MISC] = fmaxf(v, 0.f) + log1pf(expf(-fabsf(v))) + 1.f;
      }
      if (wv == 13 && t > 0) { // logits of h_t == h_new(t-1), f16
        const uint4 ch = ((const uint4*)h2u)[ln & 31];
        const uint4* wo4 = (const uint4*)(wsu + WP_WO4);
        for (int j = 0; j < 10; ++j) {
          float lv = 0.f;
          if (ln < 32) {
            const uint4 w4 = wo4[j*32 + ln];
            lv = FDOT2(w4.x, ch.x, lv); lv = FDOT2(w4.y, ch.y, lv);
            lv = FDOT2(w4.z, ch.z, lv); lv = FDOT2(w4.w, ch.w, lv);
          }
          WRED(lv);
          if (!ln) sm[SH_B10 + j] = lv + bo[j];
        }
      }
    }
    __syncthreads();

    // ===== P2: sim addr-part (int8 AT2 x f16 q); cand (int8 AC); d[s]; out_lse(t-1) =====
    if (wv < 8) {
      sm[SH_SIMA + wv*128 + ln] =
        mv_u8<4,0>(wsu + WP_AT2 + (2*wv)*1024, Q2u, SC + SC_AT2 + (2*wv)*64, ln);
      sm[SH_SIMA + wv*128 + 64 + ln] =
        mv_u8<4,0>(wsu + WP_AT2 + (2*wv + 1)*1024, Q2u, SC + SC_AT2 + (2*wv + 1)*64, ln);
    } else if (wv < 11) {
      const int p = wv - 8;
      const float cv = mv_u8<20,0>(wsu + WP_AC + p*5120, h2u, SC + SC_AC + p*64, ln);
      candh[t*192 + p*64 + ln] = f2h(fmaxf(cv, 0.f));
    } else if (wv < 15) {
      const float q0 = sm[SH_Q + 64 + ln], q1 = sm[SH_Q + 128 + ln], q2 = sm[SH_Q + 192 + ln];
      for (int s = wv - 11; s < t; s += 4) {
        float a2 = h2f(candh[s*192 + ln]) * q0
                 + h2f(candh[s*192 + 64 + ln]) * q1
                 + h2f(candh[s*192 + 128 + ln]) * q2;
        WRED(a2);
        if (!ln) sm[SH_D + s] = a2;
      }
    } else {
      if (t > 0) out_lse(sm + SH_B10, out, t - 1, bb, ln);
    }
    __syncthreads();

    // ===== P3: v = beta*(sim_a + sum_s d[s] w_s[n]); wave max =====
    const int n3 = wv * 64 + ln;
    float v = sm[SH_SIMA + n3];
    #pragma unroll 4
    for (int s = 0; s < t; ++s) v = fmaf(sm[SH_D + s], h2f(SW16[s*1024 + n3]), v);
    v *= sm[SH_MISC];
    {
      float mx = v;
      mx = fmaxf(mx, __shfl_xor(mx, 32)); mx = fmaxf(mx, __shfl_xor(mx, 16));
      mx = fmaxf(mx, __shfl_xor(mx, 8));  mx = fmaxf(mx, __shfl_xor(mx, 4));
      mx = fmaxf(mx, __shfl_xor(mx, 2));  mx = fmaxf(mx, __shfl_xor(mx, 1));
      if (!ln) sm[SH_RED + wv] = mx;
    }
    __syncthreads();

    // ===== P4: e = exp(v - gmax) -> f16 row t (unnormalized); wave sums =====
    {
      float gmx = sm[SH_RED];
      #pragma unroll
      for (int i = 1; i < 16; ++i) gmx = fmaxf(gmx, sm[SH_RED + i]);
      const float e = __expf(v - gmx);
      SW16[t*1024 + n3] = f2h(e);
      float s2 = e; WRED(s2);
      if (!ln) sm[SH_RED2 + wv] = s2;
    }
    __syncthreads();

    // ===== P5: reading_a raw partials (int8 M4 x f16 e); g[s] = w_s . w_t =====
    if (wv < 8) {
      sm[SH_RA + wv*64 + ln] =
        mv_u8<8,1>(wsu + WP_M4 + wv*2048, SW32 + t*512 + wv*64, nullptr, ln);
    } else {
      float tot = 0.f;
      #pragma unroll
      for (int i = 0; i < 16; ++i) tot += sm[SH_RED2 + i];
      const float inv = 1.0f / tot;
      const uint4 ea = ((const uint4*)(SW32 + t*512))[ln*2];
      const uint4 eb = ((const uint4*)(SW32 + t*512))[ln*2 + 1];
      for (int s = wv - 8; s < t; s += 8) {
        const uint4 wa = ((const uint4*)(SW32 + s*512))[ln*2];
        const uint4 wb = ((const uint4*)(SW32 + s*512))[ln*2 + 1];
        float a2 = 0.f;
        a2 = FDOT2(ea.x, wa.x, a2); a2 = FDOT2(ea.y, wa.y, a2);
        a2 = FDOT2(ea.z, wa.z, a2); a2 = FDOT2(ea.w, wa.w, a2);
        a2 = FDOT2(eb.x, wb.x, a2); a2 = FDOT2(eb.y, wb.y, a2);
        a2 = FDOT2(eb.z, wb.z, a2); a2 = FDOT2(eb.w, wb.w, a2);
        WRED(a2);
        if (!ln) sm[SH_G + s] = a2 * inv;
      }
    }
    __syncthreads();

    // ===== P6: assemble reading -> f16 pairs R2 =====
    if (wv == 0) {
      float tot = 0.f;
      #pragma unroll
      for (int i = 0; i < 16; ++i) tot += sm[SH_RED2 + i];
      const float inv = 1.0f / tot;
      float rsum = 0.f;
      #pragma unroll
      for (int j = 0; j < 8; ++j) rsum += sm[SH_RA + j*64 + ln];
      const float2 sc = SC[SC_M4 + ln];          // (s_a, 128 s_a - mu_a)
      const float r = sc.x * (rsum * inv) - sc.y; // Σw = 1 after normalization
      const float rh = __shfl_down(r, 1);
      if (!(ln & 1)) R2u[ln >> 1] = packh2(r, rh);
    } else if (wv < 4) {
      const int c = (wv - 1)*64 + ln;
      float r = 0.f;
      for (int s = 0; s < t; ++s) r = fmaf(h2f(candh[s*192 + c]), sm[SH_G + s], r);
      const float rh = __shfl_down(r, 1);
      if (!(ln & 1)) R2u[wv*32 + (ln >> 1)] = packh2(r, rh);
    }
    __syncthreads();

    // ===== P7: gm = Wm @ reading (12 waves full-K); normalize w row; prefetch x =====
    if (wv < 12) {
      const int g = wv >> 2, p = wv & 3;
      sm[SH_GM + g*256 + p*64 + ln] =
        mv_u8<16,0>(wsu + WP_AM + wv*4096, R2u, SC + SC_AM + wv*64, ln);
    } else if (wv < 14) {
      float tot = 0.f;
      #pragma unroll
      for (int i = 0; i < 16; ++i) tot += sm[SH_RED2 + i];
      const float inv = 1.0f / tot;
      u32* p = SW32 + t*512 + (wv - 12)*256 + ln*4;
      uint4 v4 = *(const uint4*)p;
      v4.x = packh2(h2f(v4.x & 0xffff)*inv, h2f(v4.x >> 16)*inv);
      v4.y = packh2(h2f(v4.y & 0xffff)*inv, h2f(v4.y >> 16)*inv);
      v4.z = packh2(h2f(v4.z & 0xffff)*inv, h2f(v4.z >> 16)*inv);
      v4.w = packh2(h2f(v4.w & 0xffff)*inv, h2f(v4.w >> 16)*inv);
      *(uint4*)p = v4;
    } else if (wv == 14) {
      if (t < 31 && ln < 32) {
        const int i0 = (2*ln)*32 + bb, i1 = i0 + 32;
        const float x0 = batch[(i0 >> 6)*2048 + (t+1)*64 + (i0 & 63)];
        const float x1 = batch[(i1 >> 6)*2048 + (t+1)*64 + (i1 & 63)];
        h2u[128 + ln] = packh2(x0, x1);
      }
    }
    __syncthreads();

    // ===== P8: gates, h update, hs output, pack h pairs =====
    if (tid < 256) {
      const int h = tid;
      const float g0 = sm[SH_GA0 + h] + bi[h]       + bh[h]       + sm[SH_GM + h]       + bm[h];
      const float g1 = sm[SH_GA1 + h] + bi[256 + h] + bh[256 + h] + sm[SH_GM + 256 + h] + bm[256 + h];
      const float gh2v = sm[SH_GH2 + h] + bh[512 + h];
      const float gi2v = sm[SH_GI2 + h] + bi[512 + h];
      const float gm2  = sm[SH_GM + 512 + h] + bm[512 + h];
      const float r = 1.f / (1.f + __expf(-g0));
      const float z = 1.f / (1.f + __expf(-g1));
      const float nn = tanhf(gi2v + gm2 + r * gh2v);
      const float hn = (1.f - z) * nn + z * sm[SH_HX + h];
      sm[SH_HX + h] = hn;
      out[t*8192 + h*32 + bb] = hn;
      const float hn1 = __shfl_down(hn, 1);
      if (!(tid & 1)) h2u[tid >> 1] = packh2(hn, hn1);
    }
    __syncthreads();
  }

  // ---- epilogue: out[31] ----
  if (wv == 0) {
    const uint4 ch = ((const uint4*)h2u)[ln & 31];
    const uint4* wo4 = (const uint4*)(wsu + WP_WO4);
    for (int j = 0; j < 10; ++j) {
      float lv = 0.f;
      if (ln < 32) {
        const uint4 w4 = wo4[j*32 + ln];
        lv = FDOT2(w4.x, ch.x, lv); lv = FDOT2(w4.y, ch.y, lv);
        lv = FDOT2(w4.z, ch.z, lv); lv = FDOT2(w4.w, ch.w, lv);
      }
      WRED(lv);
      if (!ln) sm[SH_B10 + j] = lv + bo[j];
    }
    out_lse(sm + SH_B10, out, 31, bb, ln);
  }
}

extern "C" void kernel_launch(void* const* d_in, const int* in_sizes, int n_in,
                              void* d_out, int out_size, void* d_ws, size_t ws_size,
                              hipStream_t stream) {
  (void)in_sizes; (void)n_in; (void)out_size; (void)ws_size;
  const float* batch = (const float*)d_in[0];
  const float* Wi    = (const float*)d_in[1];
  const float* bi    = (const float*)d_in[2];
  const float* Wh    = (const float*)d_in[3];
  const float* bh    = (const float*)d_in[4];
  const float* Wm    = (const float*)d_in[5];
  const float* bm    = (const float*)d_in[6];
  const float* Wo    = (const float*)d_in[7];
  const float* bo    = (const float*)d_in[8];
  const float* maddr = (const float*)d_in[9];
  const float* Wq    = (const float*)d_in[10];
  const float* bq    = (const float*)d_in[11];
  const float* us    = (const float*)d_in[12];
  const float* Wch   = (const float*)d_in[13];
  const float* Wci   = (const float*)d_in[14];
  u32* wsu  = (u32*)d_ws;
  float* out = (float*)d_out;

  hipFuncSetAttribute((const void*)dntm_step,
                      hipFuncAttributeMaxDynamicSharedMemorySize, 163840);

  pack_weights<<<53, 256, 0, stream>>>(Wi, Wh, Wm, Wq, Wch, Wci, maddr, Wo, wsu);
  dntm_step<<<32, 1024, SMEM_BYTES, stream>>>(batch, bi, bh, bm, bo, bq, us, wsu, out);
}

// Round 8
// 661.934 us; speedup vs baseline: 2.0443x; 1.4116x over previous
//
#include <hip/hip_runtime.h>

typedef unsigned int u32;
typedef unsigned short u16;
typedef _Float16 f16x2 __attribute__((ext_vector_type(2)));

// ---------------- problem constants ----------------
// B=32, T=32, F=64, H=256, N=1024, A=64, C=192, M=256
// out: hs [32,256,32] (262144 f32) then outs [32,10,32] (10240 f32)

// ---------------- workspace (u32 offsets), f16 k4-packed uint4 [panel][k4][64] ----------------
#define WP_A0    0        // [Wh0;Wi0] 4 panels x 40 k4 (pairs: h 0..127, x 128..159)
#define WP_A1    40960
#define WP_A2H   81920    // Wh2 4 x 32
#define WP_A2I   114688   // Wi2 4 x 8
#define WP_AQ    122880   // Wq  4 x 32
#define WP_AC    155648   // [Wch;Wci] 3 x 40
#define WP_AM    186368   // Wm  12 x 32 (gate-major)
#define WP_AT2   284672   // maddr row-pairs: 16 panels x 8 k4 (outs n, k a)
#define WP_M4    317440   // maddr col view: [128 k4][64 a] (outs a, k n-pairs)
#define WP_WO4   350208   // W_output: [10][32] uint4

// ---------------- LDS layout (f32 offsets) ----------------
#define SH_HX    0      // f32 h[256]
#define SH_H2    256    // u32[160] (h,x) f16 pairs
#define SH_Q     416    // f32 q[256] (incl bq)
#define SH_Q2    672    // u32[32] q[0..63] f16 pairs
#define SH_GA0   704    // f32 [256]
#define SH_GA1   960    // f32 [256]
#define SH_GH2Q  1216   // f32 [4][256] Wh2 k-quarters
#define SH_GI2   2240   // f32 [256]
#define SH_GM    2496   // f32 [3][256]
#define SH_GMX   3264   // f32 [256]  gm2 k-half-1 partial
#define SH_SIMA  3520   // f32 [1024]
#define SH_R2    4544   // u32 [128] reading f16 pairs
#define SH_D     4672   // f32 [32]
#define SH_G     4704   // f32 [32]
#define SH_RED   4736   // f32 [16]
#define SH_RED2  4752   // f32 [16]
#define SH_MISC  4768   // f32 [8]  [0]=beta
#define SH_B10   4776   // f32 [16]
#define SH_RA    4792   // f32 [8][64] reading_a partials
#define SH_CAND  5304   // u16[32*192] = 3072 f32 slots
#define SH_W     8376   // u16[32][1024] = 16384 f32 slots
#define SMEM_FLOATS 24760
#define SMEM_BYTES (SMEM_FLOATS*4)

#define WRED(v) { v += __shfl_xor(v,32); v += __shfl_xor(v,16); v += __shfl_xor(v,8); \
                  v += __shfl_xor(v,4);  v += __shfl_xor(v,2);  v += __shfl_xor(v,1); }

__device__ __forceinline__ f16x2 bch2(u32 u) { return __builtin_bit_cast(f16x2, u); }

#if __has_builtin(__builtin_amdgcn_fdot2)
__device__ __forceinline__ float FDOT2(u32 a, u32 b, float c) {
  return __builtin_amdgcn_fdot2(bch2(a), bch2(b), c, false);
}
#else
__device__ __forceinline__ float FDOT2(u32 a, u32 b, float c) {
  f16x2 x = bch2(a), y = bch2(b);
  return c + (float)x[0]*(float)y[0] + (float)x[1]*(float)y[1];
}
#endif

__device__ __forceinline__ u16 f2h(float x) {
  _Float16 h = (_Float16)x; return __builtin_bit_cast(u16, h);
}
__device__ __forceinline__ float h2f(u16 u) {
  return (float)__builtin_bit_cast(_Float16, u);
}
__device__ __forceinline__ u32 packh2(float lo, float hi) {
  return (u32)f2h(lo) | ((u32)f2h(hi) << 16);
}

// ---- f16 k4 matvec, 1 out/lane, layout [k4][64] uint4.
// Depth-4 rotating pipeline: 4 named (w,c) slots, each reloaded right after
// consumption, next consumed 4 k4 later (~3 slots = 12 FDOT2 of slack).
// ROLLED outer loop => small I-footprint; ~48 VGPRs => no spill at 64 budget.
template<int NK4>
__device__ __forceinline__ float mv_f16(const u32* __restrict__ Wb,
                                        const u32* __restrict__ c2, const int ln)
{
  static_assert(NK4 % 4 == 0 && NK4 >= 8, "NK4 multiple of 4, >= 8");
  const uint4* __restrict__ wp = (const uint4*)Wb + ln;
  const uint4* __restrict__ c4 = (const uint4*)c2;
  uint4 w0 = wp[0], w1 = wp[64], w2 = wp[128], w3 = wp[192];
  uint4 q0 = c4[0], q1 = c4[1], q2 = c4[2], q3 = c4[3];
  wp += 256; c4 += 4;
  float a0 = 0.f, a1 = 0.f, a2 = 0.f, a3 = 0.f;
  #pragma unroll 1
  for (int g = 0; g < NK4/4 - 1; ++g) {
    a0 = FDOT2(w0.x, q0.x, a0); a1 = FDOT2(w0.y, q0.y, a1);
    a2 = FDOT2(w0.z, q0.z, a2); a3 = FDOT2(w0.w, q0.w, a3);
    w0 = wp[0];   q0 = c4[0];
    a0 = FDOT2(w1.x, q1.x, a0); a1 = FDOT2(w1.y, q1.y, a1);
    a2 = FDOT2(w1.z, q1.z, a2); a3 = FDOT2(w1.w, q1.w, a3);
    w1 = wp[64];  q1 = c4[1];
    a0 = FDOT2(w2.x, q2.x, a0); a1 = FDOT2(w2.y, q2.y, a1);
    a2 = FDOT2(w2.z, q2.z, a2); a3 = FDOT2(w2.w, q2.w, a3);
    w2 = wp[128]; q2 = c4[2];
    a0 = FDOT2(w3.x, q3.x, a0); a1 = FDOT2(w3.y, q3.y, a1);
    a2 = FDOT2(w3.z, q3.z, a2); a3 = FDOT2(w3.w, q3.w, a3);
    w3 = wp[192]; q3 = c4[3];
    wp += 256; c4 += 4;
  }
  a0 = FDOT2(w0.x, q0.x, a0); a1 = FDOT2(w0.y, q0.y, a1);
  a2 = FDOT2(w0.z, q0.z, a2); a3 = FDOT2(w0.w, q0.w, a3);
  a0 = FDOT2(w1.x, q1.x, a0); a1 = FDOT2(w1.y, q1.y, a1);
  a2 = FDOT2(w1.z, q1.z, a2); a3 = FDOT2(w1.w, q1.w, a3);
  a0 = FDOT2(w2.x, q2.x, a0); a1 = FDOT2(w2.y, q2.y, a1);
  a2 = FDOT2(w2.z, q2.z, a2); a3 = FDOT2(w2.w, q2.w, a3);
  a0 = FDOT2(w3.x, q3.x, a0); a1 = FDOT2(w3.y, q3.y, a1);
  a2 = FDOT2(w3.z, q3.z, a2); a3 = FDOT2(w3.w, q3.w, a3);
  return (a0 + a1) + (a2 + a3);
}

// ---- dual-panel NK4=8 matvec (shared coef), one prologue (round-4 proven) ----
__device__ __forceinline__ float2 mv2_os4_8(const u32* __restrict__ W0,
    const u32* __restrict__ W1, const u32* __restrict__ c2, const int ln)
{
  const uint4* __restrict__ w0p = (const uint4*)W0 + ln;
  const uint4* __restrict__ w1p = (const uint4*)W1 + ln;
  const uint4* __restrict__ c4 = (const uint4*)c2;
  float a0=0.f,a1=0.f,a2=0.f,a3=0.f, b0=0.f,b1=0.f,b2=0.f,b3=0.f;
  uint4 wa0=w0p[0],   wa1=w0p[64],  wa2=w0p[128], wa3=w0p[192];
  uint4 ca0=c4[0],    ca1=c4[1],    ca2=c4[2],    ca3=c4[3];
  uint4 wb0=w0p[256], wb1=w0p[320], wb2=w0p[384], wb3=w0p[448];
  uint4 cb0=c4[4],    cb1=c4[5],    cb2=c4[6],    cb3=c4[7];
  a0=FDOT2(wa0.x,ca0.x,a0); a1=FDOT2(wa0.y,ca0.y,a1); a2=FDOT2(wa0.z,ca0.z,a2); a3=FDOT2(wa0.w,ca0.w,a3);
  a0=FDOT2(wa1.x,ca1.x,a0); a1=FDOT2(wa1.y,ca1.y,a1); a2=FDOT2(wa1.z,ca1.z,a2); a3=FDOT2(wa1.w,ca1.w,a3);
  a0=FDOT2(wa2.x,ca2.x,a0); a1=FDOT2(wa2.y,ca2.y,a1); a2=FDOT2(wa2.z,ca2.z,a2); a3=FDOT2(wa2.w,ca2.w,a3);
  a0=FDOT2(wa3.x,ca3.x,a0); a1=FDOT2(wa3.y,ca3.y,a1); a2=FDOT2(wa3.z,ca3.z,a2); a3=FDOT2(wa3.w,ca3.w,a3);
  wa0=w1p[0]; wa1=w1p[64]; wa2=w1p[128]; wa3=w1p[192];
  a0=FDOT2(wb0.x,cb0.x,a0); a1=FDOT2(wb0.y,cb0.y,a1); a2=FDOT2(wb0.z,cb0.z,a2); a3=FDOT2(wb0.w,cb0.w,a3);
  a0=FDOT2(wb1.x,cb1.x,a0); a1=FDOT2(wb1.y,cb1.y,a1); a2=FDOT2(wb1.z,cb1.z,a2); a3=FDOT2(wb1.w,cb1.w,a3);
  a0=FDOT2(wb2.x,cb2.x,a0); a1=FDOT2(wb2.y,cb2.y,a1); a2=FDOT2(wb2.z,cb2.z,a2); a3=FDOT2(wb2.w,cb2.w,a3);
  a0=FDOT2(wb3.x,cb3.x,a0); a1=FDOT2(wb3.y,cb3.y,a1); a2=FDOT2(wb3.z,cb3.z,a2); a3=FDOT2(wb3.w,cb3.w,a3);
  wb0=w1p[256]; wb1=w1p[320]; wb2=w1p[384]; wb3=w1p[448];
  b0=FDOT2(wa0.x,ca0.x,b0); b1=FDOT2(wa0.y,ca0.y,b1); b2=FDOT2(wa0.z,ca0.z,b2); b3=FDOT2(wa0.w,ca0.w,b3);
  b0=FDOT2(wa1.x,ca1.x,b0); b1=FDOT2(wa1.y,ca1.y,b1); b2=FDOT2(wa1.z,ca1.z,b2); b3=FDOT2(wa1.w,ca1.w,b3);
  b0=FDOT2(wa2.x,ca2.x,b0); b1=FDOT2(wa2.y,ca2.y,b1); b2=FDOT2(wa2.z,ca2.z,b2); b3=FDOT2(wa2.w,ca2.w,b3);
  b0=FDOT2(wa3.x,ca3.x,b0); b1=FDOT2(wa3.y,ca3.y,b1); b2=FDOT2(wa3.z,ca3.z,b2); b3=FDOT2(wa3.w,ca3.w,b3);
  b0=FDOT2(wb0.x,cb0.x,b0); b1=FDOT2(wb0.y,cb0.y,b1); b2=FDOT2(wb0.z,cb0.z,b2); b3=FDOT2(wb0.w,cb0.w,b3);
  b0=FDOT2(wb1.x,cb1.x,b0); b1=FDOT2(wb1.y,cb1.y,b1); b2=FDOT2(wb1.z,cb1.z,b2); b3=FDOT2(wb1.w,cb1.w,b3);
  b0=FDOT2(wb2.x,cb2.x,b0); b1=FDOT2(wb2.y,cb2.y,b1); b2=FDOT2(wb2.z,cb2.z,b2); b3=FDOT2(wb2.w,cb2.w,b3);
  b0=FDOT2(wb3.x,cb3.x,b0); b1=FDOT2(wb3.y,cb3.y,b1); b2=FDOT2(wb3.z,cb3.z,b2); b3=FDOT2(wb3.w,cb3.w,b3);
  return make_float2((a0+a1)+(a2+a3), (b0+b1)+(b2+b3));
}

__device__ __forceinline__ void out_lse(const float* __restrict__ b10,
    float* __restrict__ out, const int t_out, const int bb, const int ln)
{
  float v = (ln < 10) ? b10[ln] : -1e30f;
  float m = v;
  m = fmaxf(m, __shfl_xor(m, 8, 16));
  m = fmaxf(m, __shfl_xor(m, 4, 16));
  m = fmaxf(m, __shfl_xor(m, 2, 16));
  m = fmaxf(m, __shfl_xor(m, 1, 16));
  float e = (ln < 10) ? __expf(v - m) : 0.f;
  float s = e;
  s += __shfl_xor(s, 8, 16);
  s += __shfl_xor(s, 4, 16);
  s += __shfl_xor(s, 2, 16);
  s += __shfl_xor(s, 1, 16);
  if (ln < 10) out[262144 + t_out * 320 + ln * 32 + bb] = v - m - logf(s);
}

// ---------------- pack kernel (round-4 f16, verbatim) ----------------
__device__ __forceinline__ void pack_panel(const float* __restrict__ srcA, int KA, int np4A,
                                           const float* __restrict__ srcB, int KB,
                                           int np4tot, int o0, u32* __restrict__ dstu, int tid)
{
  uint4* d4 = (uint4*)dstu;
  for (int idx = tid; idx < np4tot * 64; idx += 256) {
    const int k4 = idx >> 6, o = idx & 63;
    const float* s = (k4 < np4A) ? (srcA + (size_t)(o0 + o) * KA + k4 * 8)
                                 : (srcB + (size_t)(o0 + o) * KB + (k4 - np4A) * 8);
    uint4 v;
    v.x = packh2(s[0], s[1]); v.y = packh2(s[2], s[3]);
    v.z = packh2(s[4], s[5]); v.w = packh2(s[6], s[7]);
    d4[idx] = v;
  }
}

__global__ void pack_weights(const float* __restrict__ Wi, const float* __restrict__ Wh,
                             const float* __restrict__ Wm, const float* __restrict__ Wq,
                             const float* __restrict__ Wch, const float* __restrict__ Wci,
                             const float* __restrict__ maddr, const float* __restrict__ Wo,
                             u32* __restrict__ wsu)
{
  const int b = blockIdx.x, tid = threadIdx.x;
  if (b < 4)        pack_panel(Wh,          256, 32, Wi,        64, 40, b*64,      wsu + WP_A0  + b*10240, tid);
  else if (b < 8)   pack_panel(Wh + 65536,  256, 32, Wi + 16384,64, 40, (b-4)*64,  wsu + WP_A1  + (b-4)*10240, tid);
  else if (b < 12)  pack_panel(Wh + 131072, 256, 32, Wh,       256, 32, (b-8)*64,  wsu + WP_A2H + (b-8)*8192, tid);
  else if (b < 16)  pack_panel(Wi + 32768,   64,  8, Wi,        64,  8, (b-12)*64, wsu + WP_A2I + (b-12)*2048, tid);
  else if (b < 20)  pack_panel(Wq,          256, 32, Wq,       256, 32, (b-16)*64, wsu + WP_AQ  + (b-16)*8192, tid);
  else if (b < 23)  pack_panel(Wch,         256, 32, Wci,       64, 40, (b-20)*64, wsu + WP_AC  + (b-20)*10240, tid);
  else if (b < 35) { int x = b-23; int g = x>>2;
                    pack_panel(Wm + g*65536, 256, 32, Wm,      256, 32, (x&3)*64,  wsu + WP_AM  + x*8192, tid); }
  else if (b < 51)  pack_panel(maddr,        64,  8, maddr,     64,  8, (b-35)*64, wsu + WP_AT2 + (b-35)*2048, tid);
  else if (b < 55) { // M4: uint4(k4, a) = n-pairs 4k4..4k4+3 of maddr column a
    const int kb = b - 51;
    uint4* d4 = (uint4*)(wsu + WP_M4);
    for (int idx = tid; idx < 2048; idx += 256) {
      const int k4 = kb*32 + (idx >> 6), a = idx & 63;
      const float* s = maddr + (size_t)(8*k4)*64 + a;
      uint4 v;
      v.x = packh2(s[0],   s[64]);  v.y = packh2(s[128], s[192]);
      v.z = packh2(s[256], s[320]); v.w = packh2(s[384], s[448]);
      d4[k4*64 + a] = v;
    }
  } else {          // WO4: [10][32] uint4 = pack8(Wo[j][8l..8l+8])
    uint4* d4 = (uint4*)(wsu + WP_WO4);
    for (int idx = tid; idx < 320; idx += 256) {
      const int j = idx >> 5, l = idx & 31;
      const float* s = Wo + j*256 + l*8;
      uint4 v;
      v.x = packh2(s[0], s[1]); v.y = packh2(s[2], s[3]);
      v.z = packh2(s[4], s[5]); v.w = packh2(s[6], s[7]);
      d4[idx] = v;
    }
  }
}

// ---------------- main persistent per-batch kernel ----------------
__global__ __launch_bounds__(1024) void dntm_step(
    const float* __restrict__ batch, const float* __restrict__ bi,
    const float* __restrict__ bh, const float* __restrict__ bm,
    const float* __restrict__ bo, const float* __restrict__ bq,
    const float* __restrict__ usharp, const u32* __restrict__ wsu,
    float* __restrict__ out)
{
  extern __shared__ float sm[];
  u32* h2u   = (u32*)(sm + SH_H2);
  u32* Q2u   = (u32*)(sm + SH_Q2);
  u32* R2u   = (u32*)(sm + SH_R2);
  u16* candh = (u16*)(sm + SH_CAND);
  u16* SW16  = (u16*)(sm + SH_W);
  u32* SW32  = (u32*)(sm + SH_W);
  const int tid = threadIdx.x, ln = tid & 63, wv = tid >> 6;
  const int bb = blockIdx.x;

  if (tid < 256) sm[SH_HX + tid] = 0.f;
  if (tid < 128) h2u[tid] = 0u;
  if (tid >= 128 && tid < 160) {
    const int j = tid - 128;
    const int i0 = (2*j)*32 + bb, i1 = i0 + 32;
    const float x0 = batch[(i0 >> 6)*2048 + (i0 & 63)];
    const float x1 = batch[(i1 >> 6)*2048 + (i1 & 63)];
    h2u[128 + j] = packh2(x0, x1);
  }
  __syncthreads();

  for (int t = 0; t < 32; ++t) {
    // ===== P1: h/x matvecs, balanced 40-48 k4/wave (A2H spread as 16 quarters) =====
    if (wv < 4) {
      sm[SH_GA0 + wv*64 + ln] = mv_f16<40>(wsu + WP_A0 + wv*10240, h2u, ln);
    } else if (wv < 8) {
      sm[SH_GA1 + (wv-4)*64 + ln] = mv_f16<40>(wsu + WP_A1 + (wv-4)*10240, h2u, ln);
    } else if (wv < 11) {
      const int p = wv - 8;
      const float cv = mv_f16<40>(wsu + WP_AC + p*10240, h2u, ln);
      candh[t*192 + p*64 + ln] = f2h(fmaxf(cv, 0.f));
    } else if (wv == 11) {
      const float2 r01 = mv2_os4_8(wsu+WP_A2I,      wsu+WP_A2I+2048, h2u+128, ln);
      const float2 r23 = mv2_os4_8(wsu+WP_A2I+4096, wsu+WP_A2I+6144, h2u+128, ln);
      sm[SH_GI2 +       ln] = r01.x; sm[SH_GI2 +  64 + ln] = r01.y;
      sm[SH_GI2 + 128 + ln] = r23.x; sm[SH_GI2 + 192 + ln] = r23.y;
      { // beta = softplus(u.h) + 1
        const float4 h4 = *(const float4*)(sm + SH_HX + ln*4);
        const float4 u4 = *(const float4*)(usharp + ln*4);
        float v = h4.x*u4.x + h4.y*u4.y + h4.z*u4.z + h4.w*u4.w;
        WRED(v);
        if (!ln) sm[SH_MISC] = fmaxf(v, 0.f) + log1pf(expf(-fabsf(v))) + 1.f;
      }
    } else {
      const int p = wv - 12;
      const float qv = mv_f16<32>(wsu + WP_AQ + p*8192, h2u, ln) + bq[p*64 + ln];
      sm[SH_Q + p*64 + ln] = qv;
      if (wv == 12) {
        const float qh = __shfl_down(qv, 1);
        if (!(ln & 1)) Q2u[ln >> 1] = packh2(qv, qh);
      }
      if (wv == 13 && t > 0) { // logits of h_t == h_new(t-1)
        const uint4 ch = ((const uint4*)h2u)[ln & 31];
        const uint4* wo4 = (const uint4*)(wsu + WP_WO4);
        for (int j = 0; j < 10; ++j) {
          float lv = 0.f;
          if (ln < 32) {
            const uint4 w4 = wo4[j*32 + ln];
            lv = FDOT2(w4.x, ch.x, lv); lv = FDOT2(w4.y, ch.y, lv);
            lv = FDOT2(w4.z, ch.z, lv); lv = FDOT2(w4.w, ch.w, lv);
          }
          WRED(lv);
          if (!ln) sm[SH_B10 + j] = lv + bo[j];
        }
      }
    }
    { // every wave: one Wh2 k-quarter (panel wv>>2, quarter wv&3)
      const int p = wv >> 2, qq = wv & 3;
      sm[SH_GH2Q + qq*256 + p*64 + ln] =
        mv_f16<8>(wsu + WP_A2H + p*8192 + qq*2048, h2u + qq*32, ln);
    }
    __syncthreads();

    // ===== P2: sim addr-part (dual-panel); d[s] = cand_s . q_c; out_lse(t-1) =====
    if (wv < 8) {
      const float2 r = mv2_os4_8(wsu + WP_AT2 + (2*wv)*2048,
                                 wsu + WP_AT2 + (2*wv+1)*2048, Q2u, ln);
      sm[SH_SIMA + wv*128 + ln]      = r.x;
      sm[SH_SIMA + wv*128 + 64 + ln] = r.y;
    } else if (wv < 15) {
      const float q0 = sm[SH_Q + 64 + ln], q1 = sm[SH_Q + 128 + ln], q2 = sm[SH_Q + 192 + ln];
      for (int s = wv - 8; s < t; s += 7) {
        float a2 = h2f(candh[s*192 + ln]) * q0
                 + h2f(candh[s*192 + 64 + ln]) * q1
                 + h2f(candh[s*192 + 128 + ln]) * q2;
        WRED(a2);
        if (!ln) sm[SH_D + s] = a2;
      }
    } else {
      if (t > 0) out_lse(sm + SH_B10, out, t - 1, bb, ln);
    }
    __syncthreads();

    // ===== P3: v = beta*(sim_a + sum_s d[s] w_s[n]); wave max =====
    const int n3 = wv * 64 + ln;
    float v = sm[SH_SIMA + n3];
    #pragma unroll 4
    for (int s = 0; s < t; ++s) v = fmaf(sm[SH_D + s], h2f(SW16[s*1024 + n3]), v);
    v *= sm[SH_MISC];
    {
      float mx = v;
      mx = fmaxf(mx, __shfl_xor(mx, 32)); mx = fmaxf(mx, __shfl_xor(mx, 16));
      mx = fmaxf(mx, __shfl_xor(mx, 8));  mx = fmaxf(mx, __shfl_xor(mx, 4));
      mx = fmaxf(mx, __shfl_xor(mx, 2));  mx = fmaxf(mx, __shfl_xor(mx, 1));
      if (!ln) sm[SH_RED + wv] = mx;
    }
    __syncthreads();

    // ===== P4: e = exp(v - gmax) -> f16 row t (unnormalized); wave sums =====
    {
      float gmx = sm[SH_RED];
      #pragma unroll
      for (int i = 1; i < 16; ++i) gmx = fmaxf(gmx, sm[SH_RED + i]);
      const float e = __expf(v - gmx);
      SW16[t*1024 + n3] = f2h(e);
      float s2 = e; WRED(s2);
      if (!ln) sm[SH_RED2 + wv] = s2;
    }
    __syncthreads();

    // ===== P5: reading_a partials (M4); g[s] = w_s . w_t =====
    {
      float tot = 0.f;
      #pragma unroll
      for (int i = 0; i < 16; ++i) tot += sm[SH_RED2 + i];
      const float inv = 1.0f / tot;
      if (wv < 8) {
        const float acc = mv_f16<16>(wsu + WP_M4 + wv*4096,
                                     SW32 + t*512 + wv*64, ln);
        sm[SH_RA + wv*64 + ln] = acc * inv;
      } else {
        const uint4 ea = ((const uint4*)(SW32 + t*512))[ln*2];
        const uint4 eb = ((const uint4*)(SW32 + t*512))[ln*2 + 1];
        for (int s = wv - 8; s < t; s += 8) {
          const uint4 wa = ((const uint4*)(SW32 + s*512))[ln*2];
          const uint4 wb = ((const uint4*)(SW32 + s*512))[ln*2 + 1];
          float a2 = 0.f;
          a2 = FDOT2(ea.x, wa.x, a2); a2 = FDOT2(ea.y, wa.y, a2);
          a2 = FDOT2(ea.z, wa.z, a2); a2 = FDOT2(ea.w, wa.w, a2);
          a2 = FDOT2(eb.x, wb.x, a2); a2 = FDOT2(eb.y, wb.y, a2);
          a2 = FDOT2(eb.z, wb.z, a2); a2 = FDOT2(eb.w, wb.w, a2);
          WRED(a2);
          if (!ln) sm[SH_G + s] = a2 * inv;
        }
      }
    }
    __syncthreads();

    // ===== P6: assemble reading -> f16 pairs R2 =====
    if (wv == 0) {
      float r = 0.f;
      #pragma unroll
      for (int j = 0; j < 8; ++j) r += sm[SH_RA + j*64 + ln];
      const float rh = __shfl_down(r, 1);
      if (!(ln & 1)) R2u[ln >> 1] = packh2(r, rh);
    } else if (wv < 4) {
      const int c = (wv - 1)*64 + ln;
      float r = 0.f;
      for (int s = 0; s < t; ++s) r = fmaf(h2f(candh[s*192 + c]), sm[SH_G + s], r);
      const float rh = __shfl_down(r, 1);
      if (!(ln & 1)) R2u[wv*32 + (ln >> 1)] = packh2(r, rh);
    }
    __syncthreads();

    // ===== P7: gm = Wm @ reading (panels 0-7 full on wv0-7; 8-11 as k-halves on wv8-15);
    //          normalize w row (wv14,15); prefetch x (wv13) =====
    if (wv < 8) {
      const int g = wv >> 2, p = wv & 3;
      sm[SH_GM + g*256 + p*64 + ln] = mv_f16<32>(wsu + WP_AM + wv*8192, R2u, ln);
    } else {
      const int idx = wv - 8, p = idx >> 1, kh = idx & 1;
      const float gv = mv_f16<16>(wsu + WP_AM + (8+p)*8192 + kh*4096, R2u + kh*64, ln);
      sm[(kh ? SH_GMX : SH_GM + 512) + p*64 + ln] = gv;
      if (wv >= 14) { // normalize w row t (2 waves x uint4)
        float tot = 0.f;
        #pragma unroll
        for (int i = 0; i < 16; ++i) tot += sm[SH_RED2 + i];
        const float inv = 1.0f / tot;
        u32* pw = SW32 + t*512 + (wv - 14)*256 + ln*4;
        uint4 v4 = *(const uint4*)pw;
        v4.x = packh2(h2f(v4.x & 0xffff)*inv, h2f(v4.x >> 16)*inv);
        v4.y = packh2(h2f(v4.y & 0xffff)*inv, h2f(v4.y >> 16)*inv);
        v4.z = packh2(h2f(v4.z & 0xffff)*inv, h2f(v4.z >> 16)*inv);
        v4.w = packh2(h2f(v4.w & 0xffff)*inv, h2f(v4.w >> 16)*inv);
        *(uint4*)pw = v4;
      } else if (wv == 13) {
        if (t < 31 && ln < 32) {
          const int i0 = (2*ln)*32 + bb, i1 = i0 + 32;
          const float x0 = batch[(i0 >> 6)*2048 + (t+1)*64 + (i0 & 63)];
          const float x1 = batch[(i1 >> 6)*2048 + (t+1)*64 + (i1 & 63)];
          h2u[128 + ln] = packh2(x0, x1);
        }
      }
    }
    __syncthreads();

    // ===== P8: gates, h update, hs output, pack h pairs =====
    if (tid < 256) {
      const int h = tid;
      const float g0 = sm[SH_GA0 + h] + bi[h]       + bh[h]       + sm[SH_GM + h]       + bm[h];
      const float g1 = sm[SH_GA1 + h] + bi[256 + h] + bh[256 + h] + sm[SH_GM + 256 + h] + bm[256 + h];
      const float gh2v = sm[SH_GH2Q + h] + sm[SH_GH2Q + 256 + h]
                       + sm[SH_GH2Q + 512 + h] + sm[SH_GH2Q + 768 + h] + bh[512 + h];
      const float gi2v = sm[SH_GI2 + h] + bi[512 + h];
      const float gm2  = sm[SH_GM + 512 + h] + sm[SH_GMX + h] + bm[512 + h];
      const float r = 1.f / (1.f + __expf(-g0));
      const float z = 1.f / (1.f + __expf(-g1));
      const float nn = tanhf(gi2v + gm2 + r * gh2v);
      const float hn = (1.f - z) * nn + z * sm[SH_HX + h];
      sm[SH_HX + h] = hn;
      out[t*8192 + h*32 + bb] = hn;
      const float hn1 = __shfl_down(hn, 1);
      if (!(tid & 1)) h2u[tid >> 1] = packh2(hn, hn1);
    }
    __syncthreads();
  }

  // ---- epilogue: out[31] ----
  if (wv == 0) {
    const uint4 ch = ((const uint4*)h2u)[ln & 31];
    const uint4* wo4 = (const uint4*)(wsu + WP_WO4);
    for (int j = 0; j < 10; ++j) {
      float lv = 0.f;
      if (ln < 32) {
        const uint4 w4 = wo4[j*32 + ln];
        lv = FDOT2(w4.x, ch.x, lv); lv = FDOT2(w4.y, ch.y, lv);
        lv = FDOT2(w4.z, ch.z, lv); lv = FDOT2(w4.w, ch.w, lv);
      }
      WRED(lv);
      if (!ln) sm[SH_B10 + j] = lv + bo[j];
    }
    out_lse(sm + SH_B10, out, 31, bb, ln);
  }
}

extern "C" void kernel_launch(void* const* d_in, const int* in_sizes, int n_in,
                              void* d_out, int out_size, void* d_ws, size_t ws_size,
                              hipStream_t stream) {
  (void)in_sizes; (void)n_in; (void)out_size; (void)ws_size;
  const float* batch = (const float*)d_in[0];
  const float* Wi    = (const float*)d_in[1];
  const float* bi    = (const float*)d_in[2];
  const float* Wh    = (const float*)d_in[3];
  const float* bh    = (const float*)d_in[4];
  const float* Wm    = (const float*)d_in[5];
  const float* bm    = (const float*)d_in[6];
  const float* Wo    = (const float*)d_in[7];
  const float* bo    = (const float*)d_in[8];
  const float* maddr = (const float*)d_in[9];
  const float* Wq    = (const float*)d_in[10];
  const float* bq    = (const float*)d_in[11];
  const float* us    = (const float*)d_in[12];
  const float* Wch   = (const float*)d_in[13];
  const float* Wci   = (const float*)d_in[14];
  u32* wsu  = (u32*)d_ws;
  float* out = (float*)d_out;

  hipFuncSetAttribute((const void*)dntm_step,
                      hipFuncAttributeMaxDynamicSharedMemorySize, 163840);

  pack_weights<<<56, 256, 0, stream>>>(Wi, Wh, Wm, Wq, Wch, Wci, maddr, Wo, wsu);
  dntm_step<<<32, 1024, SMEM_BYTES, stream>>>(batch, bi, bh, bm, bo, bq, us, wsu, out);
}